// Round 19
// baseline (413.967 us; speedup 1.0000x reference)
//
#include <hip/hip_runtime.h>
#include <hip/hip_bf16.h>
#include <cstdint>
#include <cstddef>

// ---------------- types / helpers ----------------
typedef __attribute__((ext_vector_type(8))) short short8;   // 8 x bf16 (4 VGPRs)
typedef __attribute__((ext_vector_type(4))) float f32x4;    // MFMA accumulator
typedef __attribute__((ext_vector_type(4))) unsigned short us4;

#define MFMA_BF16(a, b, c) __builtin_amdgcn_mfma_f32_16x16x32_bf16((a), (b), (c), 0, 0, 0)
#define VMCNT(n) asm volatile("s_waitcnt vmcnt(" #n ")" ::: "memory")

__device__ __forceinline__ unsigned short f2bf(float f) {  // fp32 -> bf16 RNE
  unsigned int u = __float_as_uint(f);
  u += 0x7FFFu + ((u >> 16) & 1u);
  return (unsigned short)(u >> 16);
}

// tanh-form gelu via HW exp2/rcp (~8 VALU vs ~40+ for erff+div).
__device__ __forceinline__ float gelu_fast(float v) {
  const float u = v * (0.79788456f + 0.03567741f * v * v);
  const float e = exp2f(u * 2.88539008f);          // exp(2u)
  return v - v * __builtin_amdgcn_rcpf(e + 1.0f);
}

typedef const void __attribute__((address_space(1)))* as1_cvp;
typedef void __attribute__((address_space(3)))* as3_vp;
// Always declared (host pass parses device fns); body device-only.
__device__ __forceinline__ void gll16(const short* g, short* l) {
#if defined(__HIP_DEVICE_COMPILE__)
  __builtin_amdgcn_global_load_lds((as1_cvp)g, (as3_vp)l, 16, 0, 0);
#else
  (void)g; (void)l;
#endif
}

// ---------------- prep kernels ----------------
__global__ void count_kernel(const int* __restrict__ cm, int* __restrict__ counts) {
  __shared__ int sd[256];
  const int b = blockIdx.x, t = threadIdx.x;
  int s = 0;
  for (int i = t; i < 1024; i += 256) s += cm[b * 1024 + i];
  sd[t] = s; __syncthreads();
  for (int k = 128; k > 0; k >>= 1) { if (t < k) sd[t] += sd[t + k]; __syncthreads(); }
  if (t == 0) counts[b] = sd[0];
}

__global__ void pack_bias_kernel(const float* __restrict__ bq, const float* __restrict__ bk,
                                 const float* __restrict__ bv, float* __restrict__ dst) {
  int i = blockIdx.x * 256 + threadIdx.x;
  dst[i] = (i < 1024) ? bq[i] : (i < 2048 ? bk[i - 1024] : bv[i - 2048]);
}

// src fp32 [R][C] -> dst bf16 [C][R]
__global__ void transpose_kernel(const float* __restrict__ src, unsigned short* __restrict__ dst,
                                 int R, int C) {
  __shared__ float tile[32][33];
  const int c0 = blockIdx.x * 32, r0 = blockIdx.y * 32;
  const int tx = threadIdx.x, ty = threadIdx.y;
  #pragma unroll
  for (int i = ty; i < 32; i += 8)
    tile[i][tx] = src[(size_t)(r0 + i) * C + (c0 + tx)];
  __syncthreads();
  #pragma unroll
  for (int i = ty; i < 32; i += 8)
    dst[(size_t)(c0 + i) * R + (r0 + tx)] = f2bf(tile[tx][i]);
}

// V^T precompute: qkv [B*T][3072] (V at col 2048 + h*64) -> vtr [B*H][64][1024] bf16
__global__ void vtrans_kernel(const short* __restrict__ qkv, short* __restrict__ vtr) {
  __shared__ short tile[32][33];
  const int bh = blockIdx.z;
  const int t0 = blockIdx.x * 32, d0 = blockIdx.y * 32;
  const int b = bh >> 4, h = bh & 15;
  const int tx = threadIdx.x, ty = threadIdx.y;
  const short* src = qkv + (size_t)b * 1024 * 3072 + 2048 + h * 64;
  #pragma unroll
  for (int i = ty; i < 32; i += 8)
    tile[i][tx] = src[(size_t)(t0 + i) * 3072 + d0 + tx];
  __syncthreads();
  short* dst = vtr + (size_t)bh * 65536;
  #pragma unroll
  for (int i = ty; i < 32; i += 8)
    dst[(d0 + i) * 1024 + t0 + tx] = tile[tx][i];
}

// K/V fragment pre-gather: one block per (bh, kv-tile). Writes the exact per-lane
// MFMA fragments so attention's loads are 8 fully-coalesced 1KB streams.
// kp/vp layout: [bh][tile][frag 0..3][lane 0..63][8 shorts]  (2048 shorts per tile each)
__global__ __launch_bounds__(64) void kvpack_kernel(
    const short* __restrict__ qkv, const short* __restrict__ vtr,
    short* __restrict__ kp, short* __restrict__ vp) {
  const int blk = blockIdx.x;           // bh*32 + ti
  const int bh = blk >> 5, ti = blk & 31;
  const int b = bh >> 4, h = bh & 15;
  const int l = threadIdx.x & 63;
  const int lq = l & 15, g = l >> 4;
  const int kv0 = ti * 32;
  const int permrow = 8 * (lq >> 2) + (lq & 3);
  const short* ka = qkv + (size_t)b * 1024 * 3072 + h * 64
                    + (size_t)(kv0 + permrow) * 3072 + 1024 + 8 * g;
  short* kd = kp + (size_t)blk * 2048 + l * 8;
  *(short8*)(kd)        = *(const short8*)ka;
  *(short8*)(kd + 512)  = *(const short8*)(ka + 32);
  *(short8*)(kd + 1024) = *(const short8*)(ka + 4 * 3072);
  *(short8*)(kd + 1536) = *(const short8*)(ka + 4 * 3072 + 32);
  const short* vb = vtr + (size_t)bh * 65536;
  short* vd = vp + (size_t)blk * 2048 + l * 8;
  #pragma unroll
  for (int dc = 0; dc < 4; ++dc)
    *(short8*)(vd + dc * 512) =
        *(const short8*)(vb + (16 * dc + lq) * 1024 + kv0 + 8 * g);
}

// LayerNorm over rows of 1024 fp32 -> bf16
__global__ __launch_bounds__(256) void ln_kernel(const float* __restrict__ in,
                                                 const float* __restrict__ gw,
                                                 const float* __restrict__ bw,
                                                 unsigned short* __restrict__ out) {
  const int row = blockIdx.x, t = threadIdx.x;
  const float4 v = ((const float4*)(in + (size_t)row * 1024))[t];
  float s = v.x + v.y + v.z + v.w;
  float ss = v.x * v.x + v.y * v.y + v.z * v.z + v.w * v.w;
  #pragma unroll
  for (int o = 32; o >= 1; o >>= 1) { s += __shfl_down(s, o, 64); ss += __shfl_down(ss, o, 64); }
  __shared__ float red[8];
  if ((t & 63) == 0) { red[t >> 6] = s; red[4 + (t >> 6)] = ss; }
  __syncthreads();
  const float S  = red[0] + red[1] + red[2] + red[3];
  const float SS = red[4] + red[5] + red[6] + red[7];
  const float mu = S * (1.0f / 1024.0f);
  const float var = SS * (1.0f / 1024.0f) - mu * mu;
  const float rs = rsqrtf(var + 1e-5f);
  const int c = t * 4;
  const float4 g4 = ((const float4*)gw)[t];
  const float4 b4 = ((const float4*)bw)[t];
  us4 o4;
  o4[0] = f2bf((v.x - mu) * rs * g4.x + b4.x);
  o4[1] = f2bf((v.y - mu) * rs * g4.y + b4.y);
  o4[2] = f2bf((v.z - mu) * rs * g4.z + b4.z);
  o4[3] = f2bf((v.w - mu) * rs * g4.w + b4.w);
  *(us4*)(out + (size_t)row * 1024 + c) = o4;
}

// ---------------- GEMM 128x256, BK=32, 256 threads, 2 blocks/CU (QKV, MLP1) ----------------
// EPI 0: ->bf16; 1: gelu->bf16; 3: qscale(bn<1024)->bf16.
template <int EPI>
__global__ __launch_bounds__(256, 2) void gemm128_kernel(
    const short* __restrict__ A, const short* __restrict__ BT,
    const float* __restrict__ bias, int N, int K, int gm,
    unsigned short* __restrict__ outb) {
  __shared__ alignas(16) short lds[36864];  // 3 bufs x 12288 shorts (A 4096 + B 8192)
  const int t = threadIdx.x;
  const int l = t & 63, w = t >> 6;         // wave w = col slice wc
  const int lq = l & 15, g = l >> 4;
  const int wc = w;
  const int cpx = (int)gridDim.x >> 3;
  const int wid = ((int)blockIdx.x & 7) * cpx + ((int)blockIdx.x >> 3);
  const int bm = (wid % gm) * 128, bn = (wid / gm) * 256;
  const int NT = K >> 5;

  const int csw = ((t & 3) ^ ((t >> 3) & 3)) * 8;   // pre-swizzled global k-offset (shorts)
  const int sr = t >> 2;                             // 0..63 staging row base

  const f32x4 z4 = {0.f, 0.f, 0.f, 0.f};
  f32x4 acc[8][4];
  #pragma unroll
  for (int i = 0; i < 8; i++)
    #pragma unroll
    for (int j = 0; j < 4; j++) acc[i][j] = z4;

  auto stageA = [&](int buf, int k0) {  // A tile 128x32: 2 loads
    const short* src = A + (size_t)(bm + sr) * K + k0 + csw;
    short* dst = lds + buf * 12288 + t * 8;
    gll16(src, dst);
    gll16(src + (size_t)64 * K, dst + 2048);
  };
  auto stageB = [&](int buf, int k0) {  // B tile 256x32: 4 loads
    const short* src = BT + (size_t)(bn + sr) * K + k0 + csw;
    short* dst = lds + buf * 12288 + 4096 + t * 8;
    gll16(src, dst);
    gll16(src + (size_t)64 * K,  dst + 2048);
    gll16(src + (size_t)128 * K, dst + 4096);
    gll16(src + (size_t)192 * K, dst + 6144);
  };
  const int swu = (g ^ ((lq >> 1) & 3)) * 8;   // read swizzle (shorts)
  auto rdA = [&](int buf, int mi) {
    const int ra = mi * 16 + lq;
    return *(const short8*)(lds + buf * 12288 + ra * 32 + swu);
  };
  auto rdB = [&](int buf, int ni) {
    const int rb = wc * 64 + ni * 16 + lq;
    return *(const short8*)(lds + buf * 12288 + 4096 + rb * 32 + swu);
  };

  stageA(0, 0);  stageB(0, 0);
  stageA(1, 32); stageB(1, 32);
  VMCNT(6);
  __builtin_amdgcn_s_barrier();

  int cur = 0;
  for (int v = 0; v < NT; ++v) {
    const int nx1 = (cur == 2) ? 0 : cur + 1;
    const int nx2 = (nx1 == 2) ? 0 : nx1 + 1;
    short8 a[8], b[4];
    #pragma unroll
    for (int mi = 0; mi < 8; ++mi) a[mi] = rdA(cur, mi);
    #pragma unroll
    for (int ni = 0; ni < 4; ++ni) b[ni] = rdB(cur, ni);
    if (v + 2 < NT) {
      stageA(nx2, (v + 2) * 32); stageB(nx2, (v + 2) * 32);
      VMCNT(6);
    } else {
      VMCNT(0);
    }
    __builtin_amdgcn_s_barrier();
    __builtin_amdgcn_s_setprio(1);
    #pragma unroll
    for (int mi = 0; mi < 8; ++mi)
      #pragma unroll
      for (int ni = 0; ni < 4; ++ni)
        acc[mi][ni] = MFMA_BF16(a[mi], b[ni], acc[mi][ni]);
    __builtin_amdgcn_s_setprio(0);
    cur = nx1;
  }

  // bf16 epilogue: bias(+gelu/qscale) -> LDS [128][256] bf16 -> coalesced stores
  __syncthreads();
  const float qscale = (EPI == 3 && bn < 1024) ? 0.125f * 1.44269504088896f : 1.0f;
  unsigned short* eb = (unsigned short*)lds;
  #pragma unroll
  for (int mi = 0; mi < 8; ++mi) {
    #pragma unroll
    for (int ni = 0; ni < 4; ++ni) {
      const int col = wc * 64 + ni * 16 + lq;
      const float bv = bias[bn + col];
      #pragma unroll
      for (int r = 0; r < 4; ++r) {
        const int row = mi * 16 + 4 * g + r;
        float vv = acc[mi][ni][r] + bv;
        if (EPI == 1) vv = gelu_fast(vv);
        if (EPI == 3) vv *= qscale;
        eb[row * 256 + col] = f2bf(vv);
      }
    }
  }
  __syncthreads();
  #pragma unroll
  for (int it = 0; it < 16; ++it) {
    const int unit = it * 256 + t;          // 16B units over 64KB
    const int row = unit >> 5, c8 = unit & 31;
    const short8 vv = *(const short8*)(lds + unit * 8);
    *(short8*)((short*)outb + (size_t)(bm + row) * N + bn + c8 * 8) = vv;
  }
}

// ---------------- GEMM 64x256, BK=32, 256 threads, 2 blocks/CU (proj, MLP2) ----------------
// For N=1024 fp32+residual ops: grid = (M/64)*(N/256) = 512 blocks -> 2 resident
// blocks/CU (independent sync domains). Wave tile 64x64: 16 MFMA, 8 ds_read/K-step.
// LDS 3 x 20KB = 60KB. Stage unit = 5 loads (A 1, B 4): VMCNT(5) steady, 0 at tails.
template <int EPI>
__global__ __launch_bounds__(256, 2) void gemm64_kernel(
    const short* __restrict__ A, const short* __restrict__ BT,
    const float* __restrict__ bias, int N, int K, int gm,
    float* __restrict__ outf, const float* __restrict__ res) {
  __shared__ alignas(16) short lds[30720];  // 3 bufs x 10240 shorts (A 2048 + B 8192)
  const int t = threadIdx.x;
  const int l = t & 63, w = t >> 6;
  const int lq = l & 15, g = l >> 4;
  const int wc = w;
  const int cpx = (int)gridDim.x >> 3;
  const int wid = ((int)blockIdx.x & 7) * cpx + ((int)blockIdx.x >> 3);
  const int bm = (wid % gm) * 64, bn = (wid / gm) * 256;
  const int NT = K >> 5;

  const int csw = ((t & 3) ^ ((t >> 3) & 3)) * 8;   // pre-swizzled global k-offset
  const int sr = t >> 2;                             // 0..63

  const f32x4 z4 = {0.f, 0.f, 0.f, 0.f};
  f32x4 acc[4][4];
  #pragma unroll
  for (int i = 0; i < 4; i++)
    #pragma unroll
    for (int j = 0; j < 4; j++) acc[i][j] = z4;

  auto stageA = [&](int buf, int k0) {  // A tile 64x32: 1 load
    const short* src = A + (size_t)(bm + sr) * K + k0 + csw;
    gll16(src, lds + buf * 10240 + t * 8);
  };
  auto stageB = [&](int buf, int k0) {  // B tile 256x32: 4 loads
    const short* src = BT + (size_t)(bn + sr) * K + k0 + csw;
    short* dst = lds + buf * 10240 + 2048 + t * 8;
    gll16(src, dst);
    gll16(src + (size_t)64 * K,  dst + 2048);
    gll16(src + (size_t)128 * K, dst + 4096);
    gll16(src + (size_t)192 * K, dst + 6144);
  };
  const int swu = (g ^ ((lq >> 1) & 3)) * 8;
  auto rdA = [&](int buf, int mi) {
    const int ra = mi * 16 + lq;
    return *(const short8*)(lds + buf * 10240 + ra * 32 + swu);
  };
  auto rdB = [&](int buf, int ni) {
    const int rb = wc * 64 + ni * 16 + lq;
    return *(const short8*)(lds + buf * 10240 + 2048 + rb * 32 + swu);
  };

  stageA(0, 0);  stageB(0, 0);
  stageA(1, 32); stageB(1, 32);
  VMCNT(5);
  __builtin_amdgcn_s_barrier();

  int cur = 0;
  for (int v = 0; v < NT; ++v) {
    const int nx1 = (cur == 2) ? 0 : cur + 1;
    const int nx2 = (nx1 == 2) ? 0 : nx1 + 1;
    short8 a[4], b[4];
    #pragma unroll
    for (int mi = 0; mi < 4; ++mi) a[mi] = rdA(cur, mi);
    #pragma unroll
    for (int ni = 0; ni < 4; ++ni) b[ni] = rdB(cur, ni);
    if (v + 2 < NT) {
      stageA(nx2, (v + 2) * 32); stageB(nx2, (v + 2) * 32);
      VMCNT(5);
    } else {
      VMCNT(0);
    }
    __builtin_amdgcn_s_barrier();
    __builtin_amdgcn_s_setprio(1);
    #pragma unroll
    for (int mi = 0; mi < 4; ++mi)
      #pragma unroll
      for (int ni = 0; ni < 4; ++ni)
        acc[mi][ni] = MFMA_BF16(a[mi], b[ni], acc[mi][ni]);
    __builtin_amdgcn_s_setprio(0);
    cur = nx1;
  }

  // bias + fp32 residual direct stores
  #pragma unroll
  for (int mi = 0; mi < 4; ++mi) {
    #pragma unroll
    for (int ni = 0; ni < 4; ++ni) {
      const int col = bn + wc * 64 + ni * 16 + lq;
      const float bv = bias[col];
      #pragma unroll
      for (int r = 0; r < 4; ++r) {
        const int row = bm + mi * 16 + 4 * g + r;
        const size_t idx = (size_t)row * N + col;
        outf[idx] = acc[mi][ni][r] + bv + res[idx];
      }
    }
  }
}

// ---------------- flash attention: 4-wave blocks, packed K/V fragments ----------------
__global__ __launch_bounds__(256) void attn_kernel(
    const short* __restrict__ qkv, const short* __restrict__ kp,
    const short* __restrict__ vp, unsigned short* __restrict__ y,
    const int* __restrict__ counts) {
  const int blk = blockIdx.x;
  const int slot = blk >> 3;
  const int pb = slot & 7;
  const int bh = ((slot >> 3) << 3) | (blk & 7);
  const int b = bh >> 4, h = bh & 15;
  const int w = threadIdx.x >> 6, l = threadIdx.x & 63;
  const int p = pb + 8 * w;                    // pair index 0..31
  const int lq = l & 15, g = l >> 4;
  const int qb0 = p * 16, qb1 = (63 - p) * 16;
  const int count = counts[b];

  const short* base  = qkv + (size_t)b * 1024 * 3072 + h * 64;
  const short* kbase = kp + (size_t)bh * 65536 + l * 8;   // 32 tiles x 2048 shorts
  const short* vbase = vp + (size_t)bh * 65536 + l * 8;

  short8 qf[2][2];  // [group][k-half]; B-operand col q = qb[grp]+lq (pre-scaled)
  {
    const short* qr0 = base + (size_t)(qb0 + lq) * 3072 + 8 * g;
    const short* qr1 = base + (size_t)(qb1 + lq) * 3072 + 8 * g;
    qf[0][0] = *(const short8*)qr0; qf[0][1] = *(const short8*)(qr0 + 32);
    qf[1][0] = *(const short8*)qr1; qf[1][1] = *(const short8*)(qr1 + 32);
  }

  const f32x4 z4 = {0.f, 0.f, 0.f, 0.f};
  f32x4 oacc[2][4];  // [group][dc]: O^T[d=16dc+4g+r][q]
  #pragma unroll
  for (int grp = 0; grp < 2; ++grp)
    #pragma unroll
    for (int dc = 0; dc < 4; ++dc) oacc[grp][dc] = z4;
  float mrun[2] = {-1e30f, -1e30f};
  float lrun[2] = {0.f, 0.f};                  // per-lane partial sums
  const int ncond = min((count + 31) >> 5, 8);
  const int ncausal = (qb1 + 16 - 256 + 31) >> 5;
  const int nt = ncond + ncausal;
  auto kv_of = [&](int i) { return i < ncond ? i * 32 : 256 + (i - ncond) * 32; };

  auto loadt = [&](int kv0, short8 (&kr)[4], short8 (&vr)[4]) {
    const short* kpp = kbase + (size_t)(kv0 >> 5) * 2048;
    kr[0] = *(const short8*)kpp;
    kr[1] = *(const short8*)(kpp + 512);
    kr[2] = *(const short8*)(kpp + 1024);
    kr[3] = *(const short8*)(kpp + 1536);
    const short* vpp = vbase + (size_t)(kv0 >> 5) * 2048;
    #pragma unroll
    for (int dc = 0; dc < 4; ++dc)
      vr[dc] = *(const short8*)(vpp + dc * 512);
  };

  auto compute = [&](int i, const short8 (&kr)[4], const short8 (&vr)[4]) {
    const int kv0 = kv_of(i);
    const bool isCond = (i < ncond);
    #pragma unroll
    for (int grp = 0; grp < 2; ++grp) {
      const int qb = grp ? qb1 : qb0;
      if (!isCond && kv0 >= qb + 16) continue;  // group inactive (wave-uniform)
      const bool needMask = isCond ? (kv0 + 32 > count) : (kv0 + 31 > qb);
      f32x4 sA = z4, sB = z4;  // S^T in log2 units: reg r = kv0+8g+r (A) / +4 (B)
      __builtin_amdgcn_s_setprio(1);
      sA = MFMA_BF16(kr[0], qf[grp][0], sA);
      sA = MFMA_BF16(kr[1], qf[grp][1], sA);
      sB = MFMA_BF16(kr[2], qf[grp][0], sB);
      sB = MFMA_BF16(kr[3], qf[grp][1], sB);
      __builtin_amdgcn_s_setprio(0);
      const int q = qb + lq;
      float mx = -1e30f;
      if (needMask) {
        #pragma unroll
        for (int r = 0; r < 4; ++r) {
          const int colA = kv0 + 8 * g + r, colB = colA + 4;
          const bool okA = isCond ? (colA < count) : (colA <= q);
          const bool okB = isCond ? (colB < count) : (colB <= q);
          const float vA = okA ? sA[r] : -1e30f;
          const float vB = okB ? sB[r] : -1e30f;
          sA[r] = vA; sB[r] = vB;
          mx = fmaxf(fmaxf(vA, vB), mx);
        }
      } else {
        #pragma unroll
        for (int r = 0; r < 4; ++r)
          mx = fmaxf(fmaxf(sA[r], sB[r]), mx);
      }
      mx = fmaxf(mx, __shfl_xor(mx, 16, 64));
      mx = fmaxf(mx, __shfl_xor(mx, 32, 64));
      float m = mrun[grp];
      if (!__all(mx <= m + 8.0f)) {   // defer-max: rescale only on real growth
        const float mn = fmaxf(m, mx);
        const float sf = exp2f(m - mn);   // lane-uniform
        lrun[grp] *= sf;
        #pragma unroll
        for (int dc = 0; dc < 4; ++dc)
          #pragma unroll
          for (int r = 0; r < 4; ++r) oacc[grp][dc][r] *= sf;
        mrun[grp] = mn; m = mn;
      }
      float ps = 0.f;
      #pragma unroll
      for (int r = 0; r < 4; ++r) {
        const float aa = exp2f(sA[r] - m);
        const float c2 = exp2f(sB[r] - m);
        sA[r] = aa; sB[r] = c2; ps += aa + c2;
      }
      lrun[grp] += ps;                 // per-lane partial; reduced once at the end
      union { short8 s8; __hip_bfloat162 h2[4]; } pu;  // P^T: elem j -> kv0+8g+j
      pu.h2[0] = __float22bfloat162_rn(float2{sA[0], sA[1]});
      pu.h2[1] = __float22bfloat162_rn(float2{sA[2], sA[3]});
      pu.h2[2] = __float22bfloat162_rn(float2{sB[0], sB[1]});
      pu.h2[3] = __float22bfloat162_rn(float2{sB[2], sB[3]});
      __builtin_amdgcn_s_setprio(1);
      #pragma unroll
      for (int dc = 0; dc < 4; ++dc)
        oacc[grp][dc] = MFMA_BF16(vr[dc], pu.s8, oacc[grp][dc]);
      __builtin_amdgcn_s_setprio(0);
    }
  };

  short8 kb0[4], vb0[4], kb1[4], vb1[4];
  loadt(kv_of(0), kb0, vb0);
  for (int i = 0; i < nt; i += 2) {
    if (i + 1 < nt) loadt(kv_of(i + 1), kb1, vb1);
    compute(i, kb0, vb0);
    if (i + 1 >= nt) break;
    if (i + 2 < nt) loadt(kv_of(i + 2), kb0, vb0);
    compute(i + 1, kb1, vb1);
  }

  #pragma unroll
  for (int grp = 0; grp < 2; ++grp) {
    float ls = lrun[grp];
    ls += __shfl_xor(ls, 16, 64);
    ls += __shfl_xor(ls, 32, 64);
    const float inv = 1.0f / ls;
    const int qb = grp ? qb1 : qb0;
    unsigned short* yr = y + (size_t)(b * 1024 + qb + lq) * 1024 + h * 64;
    #pragma unroll
    for (int dc = 0; dc < 4; ++dc)
      #pragma unroll
      for (int r = 0; r < 4; ++r)
        yr[16 * dc + 4 * g + r] = f2bf(oacc[grp][dc][r] * inv);
  }
}

// ---------------- launch ----------------
// Workspace (~152.1 MB):
//  [0,16M)    xn (LN1) -> kpack (after kvpack)  | act [0,64M) after attn
//  [16M,64M)  qkv
//  [64M,80M)  yb
//  [80M,112M) vtr (16M, pre-attn) -> x1 fp32 (proj output)
//  [112M,128M) vpack (pre-attn) -> hb (LN2 out, post-proj)
//  [128M,152M) weights | [152M,+12KB) bqkv | +16KB counts
extern "C" void kernel_launch(void* const* d_in, const int* in_sizes, int n_in,
                              void* d_out, int out_size, void* d_ws, size_t ws_size,
                              hipStream_t stream) {
  (void)in_sizes; (void)n_in; (void)out_size; (void)ws_size;
  const float* x     = (const float*)d_in[0];
  const float* ln1_g = (const float*)d_in[1];
  const float* ln1_b = (const float*)d_in[2];
  const float* Wq    = (const float*)d_in[3];
  const float* bq    = (const float*)d_in[4];
  const float* Wk    = (const float*)d_in[5];
  const float* bk    = (const float*)d_in[6];
  const float* Wv    = (const float*)d_in[7];
  const float* bv    = (const float*)d_in[8];
  const float* Wp    = (const float*)d_in[9];
  const float* bp    = (const float*)d_in[10];
  const float* ln2_g = (const float*)d_in[11];
  const float* ln2_b = (const float*)d_in[12];
  const float* W1    = (const float*)d_in[13];
  const float* b1    = (const float*)d_in[14];
  const float* W2    = (const float*)d_in[15];
  const float* b2    = (const float*)d_in[16];
  const int* cond_mask = (const int*)d_in[17];

  char* ws = (char*)d_ws;
  const size_t MB = 1u << 20;
  short* xn    = (short*)(ws + 0);
  short* kpack = (short*)(ws + 0);          // after xn dead
  short* qkv   = (short*)(ws + 16 * MB);
  short* act   = (short*)(ws + 0);          // after attn
  unsigned short* yb = (unsigned short*)(ws + 64 * MB);
  short* vtr   = (short*)(ws + 80 * MB);    // pre-attn scratch (x1 region)
  float* x1    = (float*)(ws + 80 * MB);
  short* vpack = (short*)(ws + 112 * MB);   // pre-attn (hb region)
  short* hb    = (short*)(ws + 112 * MB);
  short* wqkvT = (short*)(ws + 128 * MB);
  short* wpT   = (short*)(ws + 134 * MB);
  short* w1T   = (short*)(ws + 136 * MB);
  short* w2T   = (short*)(ws + 144 * MB);
  float* bqkv  = (float*)(ws + 152 * MB);
  int* counts  = (int*)(ws + 152 * MB + 16384);

  const dim3 tb(32, 8);
  count_kernel<<<8, 256, 0, stream>>>(cond_mask, counts);
  pack_bias_kernel<<<12, 256, 0, stream>>>(bq, bk, bv, bqkv);
  transpose_kernel<<<dim3(32, 32), tb, 0, stream>>>(Wq, (unsigned short*)wqkvT, 1024, 1024);
  transpose_kernel<<<dim3(32, 32), tb, 0, stream>>>(Wk, (unsigned short*)(wqkvT + 1024 * 1024), 1024, 1024);
  transpose_kernel<<<dim3(32, 32), tb, 0, stream>>>(Wv, (unsigned short*)(wqkvT + 2 * 1024 * 1024), 1024, 1024);
  transpose_kernel<<<dim3(32, 32), tb, 0, stream>>>(Wp, (unsigned short*)wpT, 1024, 1024);
  transpose_kernel<<<dim3(128, 32), tb, 0, stream>>>(W1, (unsigned short*)w1T, 1024, 4096);
  transpose_kernel<<<dim3(32, 128), tb, 0, stream>>>(W2, (unsigned short*)w2T, 4096, 1024);
  ln_kernel<<<8192, 256, 0, stream>>>(x, ln1_g, ln1_b, (unsigned short*)xn);

  // QKV: M=8192 N=3072 K=1024, 768 blocks; Q columns pre-scaled (EPI 3)
  gemm128_kernel<3><<<768, 256, 0, stream>>>(xn, wqkvT, bqkv, 3072, 1024, 64,
                                             (unsigned short*)qkv);
  vtrans_kernel<<<dim3(32, 2, 128), tb, 0, stream>>>(qkv, vtr);
  kvpack_kernel<<<4096, 64, 0, stream>>>(qkv, vtr, kpack, vpack);
  attn_kernel<<<1024, 256, 0, stream>>>(qkv, kpack, vpack, yb, counts);
  // proj: M=8192 N=1024 K=1024, 128x4=512 blocks (64x256), fp32 + residual
  gemm64_kernel<2><<<512, 256, 0, stream>>>((const short*)yb, wpT, bp, 1024, 1024, 128,
                                            x1, x);
  ln_kernel<<<8192, 256, 0, stream>>>(x1, ln2_g, ln2_b, (unsigned short*)hb);
  // MLP1: M=8192 N=4096 K=1024, 1024 blocks, gelu_fast
  gemm128_kernel<1><<<1024, 256, 0, stream>>>(hb, w1T, b1, 4096, 1024, 64,
                                              (unsigned short*)act);
  // MLP2: M=8192 N=1024 K=4096, 128x4=512 blocks (64x256), fp32 + residual
  gemm64_kernel<2><<<512, 256, 0, stream>>>(act, w2T, b2, 1024, 4096, 128,
                                            (float*)d_out, x1);
}

// Round 20
// 408.759 us; speedup vs baseline: 1.0127x; 1.0127x over previous
//
#include <hip/hip_runtime.h>
#include <hip/hip_bf16.h>
#include <cstdint>
#include <cstddef>

// ---------------- types / helpers ----------------
typedef __attribute__((ext_vector_type(8))) short short8;   // 8 x bf16 (4 VGPRs)
typedef __attribute__((ext_vector_type(4))) float f32x4;    // MFMA accumulator
typedef __attribute__((ext_vector_type(4))) unsigned short us4;

#define MFMA_BF16(a, b, c) __builtin_amdgcn_mfma_f32_16x16x32_bf16((a), (b), (c), 0, 0, 0)
#define VMCNT(n) asm volatile("s_waitcnt vmcnt(" #n ")" ::: "memory")

__device__ __forceinline__ unsigned short f2bf(float f) {  // fp32 -> bf16 RNE
  unsigned int u = __float_as_uint(f);
  u += 0x7FFFu + ((u >> 16) & 1u);
  return (unsigned short)(u >> 16);
}

// tanh-form gelu via HW exp2/rcp (~8 VALU vs ~40+ for erff+div).
__device__ __forceinline__ float gelu_fast(float v) {
  const float u = v * (0.79788456f + 0.03567741f * v * v);
  const float e = exp2f(u * 2.88539008f);          // exp(2u)
  return v - v * __builtin_amdgcn_rcpf(e + 1.0f);
}

typedef const void __attribute__((address_space(1)))* as1_cvp;
typedef void __attribute__((address_space(3)))* as3_vp;
// Always declared (host pass parses device fns); body device-only.
__device__ __forceinline__ void gll16(const short* g, short* l) {
#if defined(__HIP_DEVICE_COMPILE__)
  __builtin_amdgcn_global_load_lds((as1_cvp)g, (as3_vp)l, 16, 0, 0);
#else
  (void)g; (void)l;
#endif
}

// ---------------- prep kernels ----------------
__global__ void count_kernel(const int* __restrict__ cm, int* __restrict__ counts) {
  __shared__ int sd[256];
  const int b = blockIdx.x, t = threadIdx.x;
  int s = 0;
  for (int i = t; i < 1024; i += 256) s += cm[b * 1024 + i];
  sd[t] = s; __syncthreads();
  for (int k = 128; k > 0; k >>= 1) { if (t < k) sd[t] += sd[t + k]; __syncthreads(); }
  if (t == 0) counts[b] = sd[0];
}

__global__ void pack_bias_kernel(const float* __restrict__ bq, const float* __restrict__ bk,
                                 const float* __restrict__ bv, float* __restrict__ dst) {
  int i = blockIdx.x * 256 + threadIdx.x;
  dst[i] = (i < 1024) ? bq[i] : (i < 2048 ? bk[i - 1024] : bv[i - 2048]);
}

// src fp32 [R][C] -> dst bf16 [C][R]
__global__ void transpose_kernel(const float* __restrict__ src, unsigned short* __restrict__ dst,
                                 int R, int C) {
  __shared__ float tile[32][33];
  const int c0 = blockIdx.x * 32, r0 = blockIdx.y * 32;
  const int tx = threadIdx.x, ty = threadIdx.y;
  #pragma unroll
  for (int i = ty; i < 32; i += 8)
    tile[i][tx] = src[(size_t)(r0 + i) * C + (c0 + tx)];
  __syncthreads();
  #pragma unroll
  for (int i = ty; i < 32; i += 8)
    dst[(size_t)(c0 + i) * R + (r0 + tx)] = f2bf(tile[tx][i]);
}

// V^T precompute: qkv [B*T][3072] (V at col 2048 + h*64) -> vtr [B*H][64][1024] bf16
__global__ void vtrans_kernel(const short* __restrict__ qkv, short* __restrict__ vtr) {
  __shared__ short tile[32][33];
  const int bh = blockIdx.z;
  const int t0 = blockIdx.x * 32, d0 = blockIdx.y * 32;
  const int b = bh >> 4, h = bh & 15;
  const int tx = threadIdx.x, ty = threadIdx.y;
  const short* src = qkv + (size_t)b * 1024 * 3072 + 2048 + h * 64;
  #pragma unroll
  for (int i = ty; i < 32; i += 8)
    tile[i][tx] = src[(size_t)(t0 + i) * 3072 + d0 + tx];
  __syncthreads();
  short* dst = vtr + (size_t)bh * 65536;
  #pragma unroll
  for (int i = ty; i < 32; i += 8)
    dst[(d0 + i) * 1024 + t0 + tx] = tile[tx][i];
}

// K/V fragment pre-gather: one block per (bh, kv-tile).
// kp/vp layout: [bh][tile][frag 0..3][lane 0..63][8 shorts]
__global__ __launch_bounds__(64) void kvpack_kernel(
    const short* __restrict__ qkv, const short* __restrict__ vtr,
    short* __restrict__ kp, short* __restrict__ vp) {
  const int blk = blockIdx.x;           // bh*32 + ti
  const int bh = blk >> 5, ti = blk & 31;
  const int b = bh >> 4, h = bh & 15;
  const int l = threadIdx.x & 63;
  const int lq = l & 15, g = l >> 4;
  const int kv0 = ti * 32;
  const int permrow = 8 * (lq >> 2) + (lq & 3);
  const short* ka = qkv + (size_t)b * 1024 * 3072 + h * 64
                    + (size_t)(kv0 + permrow) * 3072 + 1024 + 8 * g;
  short* kd = kp + (size_t)blk * 2048 + l * 8;
  *(short8*)(kd)        = *(const short8*)ka;
  *(short8*)(kd + 512)  = *(const short8*)(ka + 32);
  *(short8*)(kd + 1024) = *(const short8*)(ka + 4 * 3072);
  *(short8*)(kd + 1536) = *(const short8*)(ka + 4 * 3072 + 32);
  const short* vb = vtr + (size_t)bh * 65536;
  short* vd = vp + (size_t)blk * 2048 + l * 8;
  #pragma unroll
  for (int dc = 0; dc < 4; ++dc)
    *(short8*)(vd + dc * 512) =
        *(const short8*)(vb + (16 * dc + lq) * 1024 + kv0 + 8 * g);
}

// LayerNorm over rows of 1024 fp32 -> bf16
__global__ __launch_bounds__(256) void ln_kernel(const float* __restrict__ in,
                                                 const float* __restrict__ gw,
                                                 const float* __restrict__ bw,
                                                 unsigned short* __restrict__ out) {
  const int row = blockIdx.x, t = threadIdx.x;
  const float4 v = ((const float4*)(in + (size_t)row * 1024))[t];
  float s = v.x + v.y + v.z + v.w;
  float ss = v.x * v.x + v.y * v.y + v.z * v.z + v.w * v.w;
  #pragma unroll
  for (int o = 32; o >= 1; o >>= 1) { s += __shfl_down(s, o, 64); ss += __shfl_down(ss, o, 64); }
  __shared__ float red[8];
  if ((t & 63) == 0) { red[t >> 6] = s; red[4 + (t >> 6)] = ss; }
  __syncthreads();
  const float S  = red[0] + red[1] + red[2] + red[3];
  const float SS = red[4] + red[5] + red[6] + red[7];
  const float mu = S * (1.0f / 1024.0f);
  const float var = SS * (1.0f / 1024.0f) - mu * mu;
  const float rs = rsqrtf(var + 1e-5f);
  const int c = t * 4;
  const float4 g4 = ((const float4*)gw)[t];
  const float4 b4 = ((const float4*)bw)[t];
  us4 o4;
  o4[0] = f2bf((v.x - mu) * rs * g4.x + b4.x);
  o4[1] = f2bf((v.y - mu) * rs * g4.y + b4.y);
  o4[2] = f2bf((v.z - mu) * rs * g4.z + b4.z);
  o4[3] = f2bf((v.w - mu) * rs * g4.w + b4.w);
  *(us4*)(out + (size_t)row * 1024 + c) = o4;
}

// split-K reduce: out = p0 + p1 + bias + res (fp32), N=1024 columns
__global__ __launch_bounds__(256) void red_kernel(
    const unsigned short* __restrict__ p0, const unsigned short* __restrict__ p1,
    const float* __restrict__ bias, const float* __restrict__ res,
    float* __restrict__ out) {
  const int i = (blockIdx.x * 256 + threadIdx.x) * 4;
  const us4 a = *(const us4*)(p0 + i);
  const us4 b = *(const us4*)(p1 + i);
  const float4 r = *(const float4*)(res + i);
  const float4 bv = *(const float4*)(bias + (i & 1023));
  float4 o;
  o.x = __uint_as_float((unsigned)a[0] << 16) + __uint_as_float((unsigned)b[0] << 16) + bv.x + r.x;
  o.y = __uint_as_float((unsigned)a[1] << 16) + __uint_as_float((unsigned)b[1] << 16) + bv.y + r.y;
  o.z = __uint_as_float((unsigned)a[2] << 16) + __uint_as_float((unsigned)b[2] << 16) + bv.z + r.z;
  o.w = __uint_as_float((unsigned)a[3] << 16) + __uint_as_float((unsigned)b[3] << 16) + bv.w + r.w;
  *(float4*)(out + i) = o;
}

// ---------------- unified GEMM 128x256, BK=32, 256 threads, 2 blocks/CU ----------------
// C[M,N] = A[M,K]*BT[N,K]^T (+bias). kstr = row stride (elements); K = extent.
// 4 waves, wave tile 128x64. 3-buffer LDS (3 x 24KB = 72KB). Per K-step:
// 12 ds_read_b128 -> 32 MFMAs; stage 6 gll16 into buf v+2; VMCNT(6); 1 barrier.
// EPI 0: ->bf16; 1: gelu->bf16; 2: +res(fp32)->fp32; 3: qscale(bn<1024)->bf16;
// 4: split-K partial (no bias, bf16; grid 2x: slice = wid>>8, out slice? outb:outb2,
//    A/BT advanced by slice*SKOFF elements along K).
template <int EPI>
__global__ __launch_bounds__(256, 2) void gemm128_kernel(
    const short* __restrict__ A, const short* __restrict__ BT,
    const float* __restrict__ bias, int N, int K, int kstr, int gm, int skoff,
    unsigned short* __restrict__ outb, unsigned short* __restrict__ outb2,
    float* __restrict__ outf, const float* __restrict__ res) {
  __shared__ alignas(16) short lds[36864];  // 3 bufs x 12288 shorts (A 4096 + B 8192)
  const int t = threadIdx.x;
  const int l = t & 63, w = t >> 6;         // wave w = col slice wc
  const int lq = l & 15, g = l >> 4;
  const int wc = w;
  const int cpx = (int)gridDim.x >> 3;
  int wid = ((int)blockIdx.x & 7) * cpx + ((int)blockIdx.x >> 3);
  int slice = 0;
  if (EPI == 4) { slice = wid >> 8; wid &= 255; }
  const short* Ap = A + (size_t)slice * skoff;
  const short* Bp = BT + (size_t)slice * skoff;
  unsigned short* outp = (EPI == 4 && slice) ? outb2 : outb;
  const int bm = (wid % gm) * 128, bn = (wid / gm) * 256;
  const int NT = K >> 5;

  const int csw = ((t & 3) ^ ((t >> 3) & 3)) * 8;   // pre-swizzled global k-offset (shorts)
  const int sr = t >> 2;                             // 0..63 staging row base

  const f32x4 z4 = {0.f, 0.f, 0.f, 0.f};
  f32x4 acc[8][4];
  #pragma unroll
  for (int i = 0; i < 8; i++)
    #pragma unroll
    for (int j = 0; j < 4; j++) acc[i][j] = z4;

  auto stageA = [&](int buf, int k0) {  // A tile 128x32: 2 loads
    const short* src = Ap + (size_t)(bm + sr) * kstr + k0 + csw;
    short* dst = lds + buf * 12288 + t * 8;
    gll16(src, dst);
    gll16(src + (size_t)64 * kstr, dst + 2048);
  };
  auto stageB = [&](int buf, int k0) {  // B tile 256x32: 4 loads
    const short* src = Bp + (size_t)(bn + sr) * kstr + k0 + csw;
    short* dst = lds + buf * 12288 + 4096 + t * 8;
    gll16(src, dst);
    gll16(src + (size_t)64 * kstr,  dst + 2048);
    gll16(src + (size_t)128 * kstr, dst + 4096);
    gll16(src + (size_t)192 * kstr, dst + 6144);
  };
  const int swu = (g ^ ((lq >> 1) & 3)) * 8;   // read swizzle (shorts)
  auto rdA = [&](int buf, int mi) {
    const int ra = mi * 16 + lq;
    return *(const short8*)(lds + buf * 12288 + ra * 32 + swu);
  };
  auto rdB = [&](int buf, int ni) {
    const int rb = wc * 64 + ni * 16 + lq;
    return *(const short8*)(lds + buf * 12288 + 4096 + rb * 32 + swu);
  };

  stageA(0, 0);  stageB(0, 0);
  stageA(1, 32); stageB(1, 32);
  VMCNT(6);
  __builtin_amdgcn_s_barrier();

  int cur = 0;
  for (int v = 0; v < NT; ++v) {
    const int nx1 = (cur == 2) ? 0 : cur + 1;
    const int nx2 = (nx1 == 2) ? 0 : nx1 + 1;
    short8 a[8], b[4];
    #pragma unroll
    for (int mi = 0; mi < 8; ++mi) a[mi] = rdA(cur, mi);
    #pragma unroll
    for (int ni = 0; ni < 4; ++ni) b[ni] = rdB(cur, ni);
    if (v + 2 < NT) {
      stageA(nx2, (v + 2) * 32); stageB(nx2, (v + 2) * 32);
      VMCNT(6);
    } else {
      VMCNT(0);
    }
    __builtin_amdgcn_s_barrier();
    __builtin_amdgcn_s_setprio(1);
    #pragma unroll
    for (int mi = 0; mi < 8; ++mi)
      #pragma unroll
      for (int ni = 0; ni < 4; ++ni)
        acc[mi][ni] = MFMA_BF16(a[mi], b[ni], acc[mi][ni]);
    __builtin_amdgcn_s_setprio(0);
    cur = nx1;
  }

  if (EPI == 2) {
    // bias + fp32 residual direct stores
    #pragma unroll
    for (int mi = 0; mi < 8; ++mi) {
      #pragma unroll
      for (int ni = 0; ni < 4; ++ni) {
        const int col = bn + wc * 64 + ni * 16 + lq;
        const float bv = bias[col];
        #pragma unroll
        for (int r = 0; r < 4; ++r) {
          const int row = bm + mi * 16 + 4 * g + r;
          const size_t idx = (size_t)row * N + col;
          outf[idx] = acc[mi][ni][r] + bv + res[idx];
        }
      }
    }
    return;
  }

  // bf16 epilogue: (bias/gelu/qscale/none) -> LDS [128][256] bf16 -> coalesced stores
  __syncthreads();
  const float qscale = (EPI == 3 && bn < 1024) ? 0.125f * 1.44269504088896f : 1.0f;
  unsigned short* eb = (unsigned short*)lds;
  #pragma unroll
  for (int mi = 0; mi < 8; ++mi) {
    #pragma unroll
    for (int ni = 0; ni < 4; ++ni) {
      const int col = wc * 64 + ni * 16 + lq;
      const float bv = (EPI == 4) ? 0.f : bias[bn + col];
      #pragma unroll
      for (int r = 0; r < 4; ++r) {
        const int row = mi * 16 + 4 * g + r;
        float vv = acc[mi][ni][r] + bv;
        if (EPI == 1) vv = gelu_fast(vv);
        if (EPI == 3) vv *= qscale;
        eb[row * 256 + col] = f2bf(vv);
      }
    }
  }
  __syncthreads();
  #pragma unroll
  for (int it = 0; it < 16; ++it) {
    const int unit = it * 256 + t;          // 16B units over 64KB
    const int row = unit >> 5, c8 = unit & 31;
    const short8 vv = *(const short8*)(lds + unit * 8);
    *(short8*)((short*)outp + (size_t)(bm + row) * N + bn + c8 * 8) = vv;
  }
}

// ---------------- flash attention: 4-wave blocks, packed K/V fragments ----------------
__global__ __launch_bounds__(256) void attn_kernel(
    const short* __restrict__ qkv, const short* __restrict__ kp,
    const short* __restrict__ vp, unsigned short* __restrict__ y,
    const int* __restrict__ counts) {
  const int blk = blockIdx.x;
  const int slot = blk >> 3;
  const int pb = slot & 7;
  const int bh = ((slot >> 3) << 3) | (blk & 7);
  const int b = bh >> 4, h = bh & 15;
  const int w = threadIdx.x >> 6, l = threadIdx.x & 63;
  const int p = pb + 8 * w;                    // pair index 0..31
  const int lq = l & 15, g = l >> 4;
  const int qb0 = p * 16, qb1 = (63 - p) * 16;
  const int count = counts[b];

  const short* base  = qkv + (size_t)b * 1024 * 3072 + h * 64;
  const short* kbase = kp + (size_t)bh * 65536 + l * 8;   // 32 tiles x 2048 shorts
  const short* vbase = vp + (size_t)bh * 65536 + l * 8;

  short8 qf[2][2];  // [group][k-half]; B-operand col q = qb[grp]+lq (pre-scaled)
  {
    const short* qr0 = base + (size_t)(qb0 + lq) * 3072 + 8 * g;
    const short* qr1 = base + (size_t)(qb1 + lq) * 3072 + 8 * g;
    qf[0][0] = *(const short8*)qr0; qf[0][1] = *(const short8*)(qr0 + 32);
    qf[1][0] = *(const short8*)qr1; qf[1][1] = *(const short8*)(qr1 + 32);
  }

  const f32x4 z4 = {0.f, 0.f, 0.f, 0.f};
  f32x4 oacc[2][4];  // [group][dc]: O^T[d=16dc+4g+r][q]
  #pragma unroll
  for (int grp = 0; grp < 2; ++grp)
    #pragma unroll
    for (int dc = 0; dc < 4; ++dc) oacc[grp][dc] = z4;
  float mrun[2] = {-1e30f, -1e30f};
  float lrun[2] = {0.f, 0.f};                  // per-lane partial sums
  const int ncond = min((count + 31) >> 5, 8);
  const int ncausal = (qb1 + 16 - 256 + 31) >> 5;
  const int nt = ncond + ncausal;
  auto kv_of = [&](int i) { return i < ncond ? i * 32 : 256 + (i - ncond) * 32; };

  auto loadt = [&](int kv0, short8 (&kr)[4], short8 (&vr)[4]) {
    const short* kpp = kbase + (size_t)(kv0 >> 5) * 2048;
    kr[0] = *(const short8*)kpp;
    kr[1] = *(const short8*)(kpp + 512);
    kr[2] = *(const short8*)(kpp + 1024);
    kr[3] = *(const short8*)(kpp + 1536);
    const short* vpp = vbase + (size_t)(kv0 >> 5) * 2048;
    #pragma unroll
    for (int dc = 0; dc < 4; ++dc)
      vr[dc] = *(const short8*)(vpp + dc * 512);
  };

  auto compute = [&](int i, const short8 (&kr)[4], const short8 (&vr)[4]) {
    const int kv0 = kv_of(i);
    const bool isCond = (i < ncond);
    #pragma unroll
    for (int grp = 0; grp < 2; ++grp) {
      const int qb = grp ? qb1 : qb0;
      if (!isCond && kv0 >= qb + 16) continue;  // group inactive (wave-uniform)
      const bool needMask = isCond ? (kv0 + 32 > count) : (kv0 + 31 > qb);
      f32x4 sA = z4, sB = z4;  // S^T in log2 units: reg r = kv0+8g+r (A) / +4 (B)
      __builtin_amdgcn_s_setprio(1);
      sA = MFMA_BF16(kr[0], qf[grp][0], sA);
      sA = MFMA_BF16(kr[1], qf[grp][1], sA);
      sB = MFMA_BF16(kr[2], qf[grp][0], sB);
      sB = MFMA_BF16(kr[3], qf[grp][1], sB);
      __builtin_amdgcn_s_setprio(0);
      const int q = qb + lq;
      float mx = -1e30f;
      if (needMask) {
        #pragma unroll
        for (int r = 0; r < 4; ++r) {
          const int colA = kv0 + 8 * g + r, colB = colA + 4;
          const bool okA = isCond ? (colA < count) : (colA <= q);
          const bool okB = isCond ? (colB < count) : (colB <= q);
          const float vA = okA ? sA[r] : -1e30f;
          const float vB = okB ? sB[r] : -1e30f;
          sA[r] = vA; sB[r] = vB;
          mx = fmaxf(fmaxf(vA, vB), mx);
        }
      } else {
        #pragma unroll
        for (int r = 0; r < 4; ++r)
          mx = fmaxf(fmaxf(sA[r], sB[r]), mx);
      }
      mx = fmaxf(mx, __shfl_xor(mx, 16, 64));
      mx = fmaxf(mx, __shfl_xor(mx, 32, 64));
      float m = mrun[grp];
      if (!__all(mx <= m + 8.0f)) {   // defer-max: rescale only on real growth
        const float mn = fmaxf(m, mx);
        const float sf = exp2f(m - mn);   // lane-uniform
        lrun[grp] *= sf;
        #pragma unroll
        for (int dc = 0; dc < 4; ++dc)
          #pragma unroll
          for (int r = 0; r < 4; ++r) oacc[grp][dc][r] *= sf;
        mrun[grp] = mn; m = mn;
      }
      float ps = 0.f;
      #pragma unroll
      for (int r = 0; r < 4; ++r) {
        const float aa = exp2f(sA[r] - m);
        const float c2 = exp2f(sB[r] - m);
        sA[r] = aa; sB[r] = c2; ps += aa + c2;
      }
      lrun[grp] += ps;                 // per-lane partial; reduced once at the end
      union { short8 s8; __hip_bfloat162 h2[4]; } pu;  // P^T: elem j -> kv0+8g+j
      pu.h2[0] = __float22bfloat162_rn(float2{sA[0], sA[1]});
      pu.h2[1] = __float22bfloat162_rn(float2{sA[2], sA[3]});
      pu.h2[2] = __float22bfloat162_rn(float2{sB[0], sB[1]});
      pu.h2[3] = __float22bfloat162_rn(float2{sB[2], sB[3]});
      __builtin_amdgcn_s_setprio(1);
      #pragma unroll
      for (int dc = 0; dc < 4; ++dc)
        oacc[grp][dc] = MFMA_BF16(vr[dc], pu.s8, oacc[grp][dc]);
      __builtin_amdgcn_s_setprio(0);
    }
  };

  short8 kb0[4], vb0[4], kb1[4], vb1[4];
  loadt(kv_of(0), kb0, vb0);
  for (int i = 0; i < nt; i += 2) {
    if (i + 1 < nt) loadt(kv_of(i + 1), kb1, vb1);
    compute(i, kb0, vb0);
    if (i + 1 >= nt) break;
    if (i + 2 < nt) loadt(kv_of(i + 2), kb0, vb0);
    compute(i + 1, kb1, vb1);
  }

  #pragma unroll
  for (int grp = 0; grp < 2; ++grp) {
    float ls = lrun[grp];
    ls += __shfl_xor(ls, 16, 64);
    ls += __shfl_xor(ls, 32, 64);
    const float inv = 1.0f / ls;
    const int qb = grp ? qb1 : qb0;
    unsigned short* yr = y + (size_t)(b * 1024 + qb + lq) * 1024 + h * 64;
    #pragma unroll
    for (int dc = 0; dc < 4; ++dc)
      #pragma unroll
      for (int r = 0; r < 4; ++r)
        yr[16 * dc + 4 * g + r] = f2bf(oacc[grp][dc][r] * inv);
  }
}

// ---------------- launch ----------------
// Workspace (~152.1 MB):
//  [0,16M)    xn (LN1) -> kpack  | act [0,64M) after attn
//  [16M,64M)  qkv
//  [64M,80M)  yb (attn out; dead after proj) -> MLP2 partial p0
//  [80M,112M) vtr (pre-attn) -> x1 fp32 (proj output, residual for MLP2)
//  [112M,128M) vpack (pre-attn) -> hb (LN2 out; dead after MLP1) -> MLP2 partial p1
//  [128M,152M) weights | [152M,+12KB) bqkv | +16KB counts
extern "C" void kernel_launch(void* const* d_in, const int* in_sizes, int n_in,
                              void* d_out, int out_size, void* d_ws, size_t ws_size,
                              hipStream_t stream) {
  (void)in_sizes; (void)n_in; (void)out_size; (void)ws_size;
  const float* x     = (const float*)d_in[0];
  const float* ln1_g = (const float*)d_in[1];
  const float* ln1_b = (const float*)d_in[2];
  const float* Wq    = (const float*)d_in[3];
  const float* bq    = (const float*)d_in[4];
  const float* Wk    = (const float*)d_in[5];
  const float* bk    = (const float*)d_in[6];
  const float* Wv    = (const float*)d_in[7];
  const float* bv    = (const float*)d_in[8];
  const float* Wp    = (const float*)d_in[9];
  const float* bp    = (const float*)d_in[10];
  const float* ln2_g = (const float*)d_in[11];
  const float* ln2_b = (const float*)d_in[12];
  const float* W1    = (const float*)d_in[13];
  const float* b1    = (const float*)d_in[14];
  const float* W2    = (const float*)d_in[15];
  const float* b2    = (const float*)d_in[16];
  const int* cond_mask = (const int*)d_in[17];

  char* ws = (char*)d_ws;
  const size_t MB = 1u << 20;
  short* xn    = (short*)(ws + 0);
  short* kpack = (short*)(ws + 0);          // after xn dead
  short* qkv   = (short*)(ws + 16 * MB);
  short* act   = (short*)(ws + 0);          // after attn
  unsigned short* yb = (unsigned short*)(ws + 64 * MB);
  unsigned short* part0 = (unsigned short*)(ws + 64 * MB);   // after proj (yb dead)
  short* vtr   = (short*)(ws + 80 * MB);    // pre-attn scratch (x1 region)
  float* x1    = (float*)(ws + 80 * MB);
  short* vpack = (short*)(ws + 112 * MB);   // pre-attn (hb region)
  short* hb    = (short*)(ws + 112 * MB);
  unsigned short* part1 = (unsigned short*)(ws + 112 * MB);  // after MLP1 (hb dead)
  short* wqkvT = (short*)(ws + 128 * MB);
  short* wpT   = (short*)(ws + 134 * MB);
  short* w1T   = (short*)(ws + 136 * MB);
  short* w2T   = (short*)(ws + 144 * MB);
  float* bqkv  = (float*)(ws + 152 * MB);
  int* counts  = (int*)(ws + 152 * MB + 16384);

  const dim3 tb(32, 8);
  count_kernel<<<8, 256, 0, stream>>>(cond_mask, counts);
  pack_bias_kernel<<<12, 256, 0, stream>>>(bq, bk, bv, bqkv);
  transpose_kernel<<<dim3(32, 32), tb, 0, stream>>>(Wq, (unsigned short*)wqkvT, 1024, 1024);
  transpose_kernel<<<dim3(32, 32), tb, 0, stream>>>(Wk, (unsigned short*)(wqkvT + 1024 * 1024), 1024, 1024);
  transpose_kernel<<<dim3(32, 32), tb, 0, stream>>>(Wv, (unsigned short*)(wqkvT + 2 * 1024 * 1024), 1024, 1024);
  transpose_kernel<<<dim3(32, 32), tb, 0, stream>>>(Wp, (unsigned short*)wpT, 1024, 1024);
  transpose_kernel<<<dim3(128, 32), tb, 0, stream>>>(W1, (unsigned short*)w1T, 1024, 4096);
  transpose_kernel<<<dim3(32, 128), tb, 0, stream>>>(W2, (unsigned short*)w2T, 4096, 1024);
  ln_kernel<<<8192, 256, 0, stream>>>(x, ln1_g, ln1_b, (unsigned short*)xn);

  // QKV: M=8192 N=3072 K=1024, 768 blocks; Q columns pre-scaled (EPI 3)
  gemm128_kernel<3><<<768, 256, 0, stream>>>(xn, wqkvT, bqkv, 3072, 1024, 1024, 64, 0,
                                             (unsigned short*)qkv, nullptr, nullptr, nullptr);
  vtrans_kernel<<<dim3(32, 2, 128), tb, 0, stream>>>(qkv, vtr);
  kvpack_kernel<<<4096, 64, 0, stream>>>(qkv, vtr, kpack, vpack);
  attn_kernel<<<1024, 256, 0, stream>>>(qkv, kpack, vpack, yb, counts);
  // proj: M=8192 N=1024 K=1024, 256 blocks, fp32 + residual (EPI 2)
  gemm128_kernel<2><<<256, 256, 0, stream>>>((const short*)yb, wpT, bp, 1024, 1024, 1024, 64, 0,
                                             nullptr, nullptr, x1, x);
  ln_kernel<<<8192, 256, 0, stream>>>(x1, ln2_g, ln2_b, (unsigned short*)hb);
  // MLP1: M=8192 N=4096 K=1024, 1024 blocks, gelu_fast (EPI 1)
  gemm128_kernel<1><<<1024, 256, 0, stream>>>(hb, w1T, b1, 4096, 1024, 1024, 64, 0,
                                              (unsigned short*)act, nullptr, nullptr, nullptr);
  // MLP2 split-K: M=8192 N=1024, K=4096 -> 2 slices of 2048; 512 blocks (EPI 4)
  gemm128_kernel<4><<<512, 256, 0, stream>>>(act, w2T, nullptr, 1024, 2048, 4096, 64, 2048,
                                             part0, part1, nullptr, nullptr);
  // reduce: out = p0 + p1 + b2 + x1
  red_kernel<<<8192, 256, 0, stream>>>(part0, part1, b2, x1, (float*)d_out);
}

// Round 21
// 389.245 us; speedup vs baseline: 1.0635x; 1.0501x over previous
//
#include <hip/hip_runtime.h>
#include <hip/hip_bf16.h>
#include <cstdint>
#include <cstddef>

// ---------------- types / helpers ----------------
typedef __attribute__((ext_vector_type(8))) short short8;   // 8 x bf16 (4 VGPRs)
typedef __attribute__((ext_vector_type(4))) float f32x4;    // MFMA accumulator
typedef __attribute__((ext_vector_type(4))) unsigned short us4;

#define MFMA_BF16(a, b, c) __builtin_amdgcn_mfma_f32_16x16x32_bf16((a), (b), (c), 0, 0, 0)
#define VMCNT(n) asm volatile("s_waitcnt vmcnt(" #n ")" ::: "memory")

__device__ __forceinline__ unsigned short f2bf(float f) {  // fp32 -> bf16 RNE
  unsigned int u = __float_as_uint(f);
  u += 0x7FFFu + ((u >> 16) & 1u);
  return (unsigned short)(u >> 16);
}

// tanh-form gelu via HW exp2/rcp (~8 VALU vs ~40+ for erff+div).
__device__ __forceinline__ float gelu_fast(float v) {
  const float u = v * (0.79788456f + 0.03567741f * v * v);
  const float e = exp2f(u * 2.88539008f);          // exp(2u)
  return v - v * __builtin_amdgcn_rcpf(e + 1.0f);
}

typedef const void __attribute__((address_space(1)))* as1_cvp;
typedef void __attribute__((address_space(3)))* as3_vp;
// Always declared (host pass parses device fns); body device-only.
__device__ __forceinline__ void gll16(const short* g, short* l) {
#if defined(__HIP_DEVICE_COMPILE__)
  __builtin_amdgcn_global_load_lds((as1_cvp)g, (as3_vp)l, 16, 0, 0);
#else
  (void)g; (void)l;
#endif
}

// ---------------- merged prep: blocks 0..11 pack bias, 12..19 count ----------------
__global__ void prep_kernel(const int* __restrict__ cm, int* __restrict__ counts,
                            const float* __restrict__ bq, const float* __restrict__ bk,
                            const float* __restrict__ bv, float* __restrict__ dst) {
  const int t = threadIdx.x;
  if (blockIdx.x < 12) {
    const int i = blockIdx.x * 256 + t;
    dst[i] = (i < 1024) ? bq[i] : (i < 2048 ? bk[i - 1024] : bv[i - 2048]);
    return;
  }
  __shared__ int sd[256];
  const int b = blockIdx.x - 12;
  int s = 0;
  for (int i = t; i < 1024; i += 256) s += cm[b * 1024 + i];
  sd[t] = s; __syncthreads();
  for (int k = 128; k > 0; k >>= 1) { if (t < k) sd[t] += sd[t + k]; __syncthreads(); }
  if (t == 0) counts[b] = sd[0];
}

// merged 4x 1024x1024 transpose: z = {Wq, Wk, Wv, Wp}
__global__ void transpose4_kernel(const float* __restrict__ Wq, const float* __restrict__ Wk,
                                  const float* __restrict__ Wv, const float* __restrict__ Wp,
                                  unsigned short* __restrict__ wqkvT,
                                  unsigned short* __restrict__ wpT) {
  __shared__ float tile[32][33];
  const int z = blockIdx.z;
  const float* src = (z == 0) ? Wq : (z == 1) ? Wk : (z == 2) ? Wv : Wp;
  unsigned short* dst = (z < 3) ? wqkvT + (size_t)z * 1024 * 1024 : wpT;
  const int c0 = blockIdx.x * 32, r0 = blockIdx.y * 32;
  const int tx = threadIdx.x, ty = threadIdx.y;
  #pragma unroll
  for (int i = ty; i < 32; i += 8)
    tile[i][tx] = src[(size_t)(r0 + i) * 1024 + (c0 + tx)];
  __syncthreads();
  #pragma unroll
  for (int i = ty; i < 32; i += 8)
    dst[(size_t)(c0 + i) * 1024 + (r0 + tx)] = f2bf(tile[tx][i]);
}

// src fp32 [R][C] -> dst bf16 [C][R]  (W1, W2)
__global__ void transpose_kernel(const float* __restrict__ src, unsigned short* __restrict__ dst,
                                 int R, int C) {
  __shared__ float tile[32][33];
  const int c0 = blockIdx.x * 32, r0 = blockIdx.y * 32;
  const int tx = threadIdx.x, ty = threadIdx.y;
  #pragma unroll
  for (int i = ty; i < 32; i += 8)
    tile[i][tx] = src[(size_t)(r0 + i) * C + (c0 + tx)];
  __syncthreads();
  #pragma unroll
  for (int i = ty; i < 32; i += 8)
    dst[(size_t)(c0 + i) * R + (r0 + tx)] = f2bf(tile[tx][i]);
}

// K/V fragment pre-gather with integrated V-transpose: one block per (bh, kv-tile).
// K fragments read directly (permrow scatter, absorbed once here); V tile 32x64 is
// bounced through LDS so the fragment gather needs no separate vtrans pass.
// kp/vp layout: [bh][tile][frag 0..3][lane 0..63][8 shorts]
__global__ __launch_bounds__(64) void kvpack_kernel(
    const short* __restrict__ qkv, short* __restrict__ kp, short* __restrict__ vp) {
  __shared__ short vt[32][72];          // V rows kv0..+31 x 64 cols (pad 8)
  const int blk = blockIdx.x;           // bh*32 + ti
  const int bh = blk >> 5, ti = blk & 31;
  const int b = bh >> 4, h = bh & 15;
  const int l = threadIdx.x & 63;
  const int lq = l & 15, g = l >> 4;
  const int kv0 = ti * 32;
  // load V tile: 256 short8 units, 4 per thread
  const short* vsrc = qkv + (size_t)b * 1024 * 3072 + 2048 + h * 64;
  #pragma unroll
  for (int i = 0; i < 4; ++i) {
    const int u = l * 4 + i;            // 0..255
    const int row = u >> 3, c8 = u & 7;
    *(short8*)&vt[row][c8 * 8] = *(const short8*)(vsrc + (size_t)(kv0 + row) * 3072 + c8 * 8);
  }
  // K fragments (global scatter, once)
  const int permrow = 8 * (lq >> 2) + (lq & 3);
  const short* ka = qkv + (size_t)b * 1024 * 3072 + h * 64
                    + (size_t)(kv0 + permrow) * 3072 + 1024 + 8 * g;
  short* kd = kp + (size_t)blk * 2048 + l * 8;
  *(short8*)(kd)        = *(const short8*)ka;
  *(short8*)(kd + 512)  = *(const short8*)(ka + 32);
  *(short8*)(kd + 1024) = *(const short8*)(ka + 4 * 3072);
  *(short8*)(kd + 1536) = *(const short8*)(ka + 4 * 3072 + 32);
  __syncthreads();
  // V fragments: elem j of frag dc = V[kv0+8g+j][16dc+lq] = vt[8g+j][16dc+lq]
  short* vd = vp + (size_t)blk * 2048 + l * 8;
  #pragma unroll
  for (int dc = 0; dc < 4; ++dc) {
    short8 vv;
    #pragma unroll
    for (int j = 0; j < 8; ++j) vv[j] = vt[8 * g + j][16 * dc + lq];
    *(short8*)(vd + dc * 512) = vv;
  }
}

// LayerNorm over rows of 1024 fp32 -> bf16
__global__ __launch_bounds__(256) void ln_kernel(const float* __restrict__ in,
                                                 const float* __restrict__ gw,
                                                 const float* __restrict__ bw,
                                                 unsigned short* __restrict__ out) {
  const int row = blockIdx.x, t = threadIdx.x;
  const float4 v = ((const float4*)(in + (size_t)row * 1024))[t];
  float s = v.x + v.y + v.z + v.w;
  float ss = v.x * v.x + v.y * v.y + v.z * v.z + v.w * v.w;
  #pragma unroll
  for (int o = 32; o >= 1; o >>= 1) { s += __shfl_down(s, o, 64); ss += __shfl_down(ss, o, 64); }
  __shared__ float red[8];
  if ((t & 63) == 0) { red[t >> 6] = s; red[4 + (t >> 6)] = ss; }
  __syncthreads();
  const float S  = red[0] + red[1] + red[2] + red[3];
  const float SS = red[4] + red[5] + red[6] + red[7];
  const float mu = S * (1.0f / 1024.0f);
  const float var = SS * (1.0f / 1024.0f) - mu * mu;
  const float rs = rsqrtf(var + 1e-5f);
  const int c = t * 4;
  const float4 g4 = ((const float4*)gw)[t];
  const float4 b4 = ((const float4*)bw)[t];
  us4 o4;
  o4[0] = f2bf((v.x - mu) * rs * g4.x + b4.x);
  o4[1] = f2bf((v.y - mu) * rs * g4.y + b4.y);
  o4[2] = f2bf((v.z - mu) * rs * g4.z + b4.z);
  o4[3] = f2bf((v.w - mu) * rs * g4.w + b4.w);
  *(us4*)(out + (size_t)row * 1024 + c) = o4;
}

// split-K reduce: out = p0 + p1 + bias + res (fp32), N=1024 columns
__global__ __launch_bounds__(256) void red_kernel(
    const unsigned short* __restrict__ p0, const unsigned short* __restrict__ p1,
    const float* __restrict__ bias, const float* __restrict__ res,
    float* __restrict__ out) {
  const int i = (blockIdx.x * 256 + threadIdx.x) * 4;
  const us4 a = *(const us4*)(p0 + i);
  const us4 b = *(const us4*)(p1 + i);
  const float4 r = *(const float4*)(res + i);
  const float4 bv = *(const float4*)(bias + (i & 1023));
  float4 o;
  o.x = __uint_as_float((unsigned)a[0] << 16) + __uint_as_float((unsigned)b[0] << 16) + bv.x + r.x;
  o.y = __uint_as_float((unsigned)a[1] << 16) + __uint_as_float((unsigned)b[1] << 16) + bv.y + r.y;
  o.z = __uint_as_float((unsigned)a[2] << 16) + __uint_as_float((unsigned)b[2] << 16) + bv.z + r.z;
  o.w = __uint_as_float((unsigned)a[3] << 16) + __uint_as_float((unsigned)b[3] << 16) + bv.w + r.w;
  *(float4*)(out + i) = o;
}

// ---------------- unified GEMM 128x256, BK=32, 256 threads, 2 blocks/CU ----------------
// C[M,N] = A[M,K]*BT[N,K]^T (+bias). kstr = row stride (elements); K = extent.
// 4 waves, wave tile 128x64. 3-buffer LDS (3 x 24KB = 72KB). Per K-step:
// 12 ds_read_b128 -> 32 MFMAs; stage 6 gll16 into buf v+2; VMCNT(6); 1 barrier.
// EPI 0: ->bf16; 1: gelu->bf16; 2: +res(fp32)->fp32; 3: qscale(bn<1024)->bf16;
// 4: split-K partial (no bias, bf16; grid 2x: slice = wid>>8, out slice? outb:outb2,
//    A/BT advanced by slice*SKOFF elements along K).
template <int EPI>
__global__ __launch_bounds__(256, 2) void gemm128_kernel(
    const short* __restrict__ A, const short* __restrict__ BT,
    const float* __restrict__ bias, int N, int K, int kstr, int gm, int skoff,
    unsigned short* __restrict__ outb, unsigned short* __restrict__ outb2,
    float* __restrict__ outf, const float* __restrict__ res) {
  __shared__ alignas(16) short lds[36864];  // 3 bufs x 12288 shorts (A 4096 + B 8192)
  const int t = threadIdx.x;
  const int l = t & 63, w = t >> 6;         // wave w = col slice wc
  const int lq = l & 15, g = l >> 4;
  const int wc = w;
  const int cpx = (int)gridDim.x >> 3;
  int wid = ((int)blockIdx.x & 7) * cpx + ((int)blockIdx.x >> 3);
  int slice = 0;
  if (EPI == 4) { slice = wid >> 8; wid &= 255; }
  const short* Ap = A + (size_t)slice * skoff;
  const short* Bp = BT + (size_t)slice * skoff;
  unsigned short* outp = (EPI == 4 && slice) ? outb2 : outb;
  const int bm = (wid % gm) * 128, bn = (wid / gm) * 256;
  const int NT = K >> 5;

  const int csw = ((t & 3) ^ ((t >> 3) & 3)) * 8;   // pre-swizzled global k-offset (shorts)
  const int sr = t >> 2;                             // 0..63 staging row base

  const f32x4 z4 = {0.f, 0.f, 0.f, 0.f};
  f32x4 acc[8][4];
  #pragma unroll
  for (int i = 0; i < 8; i++)
    #pragma unroll
    for (int j = 0; j < 4; j++) acc[i][j] = z4;

  auto stageA = [&](int buf, int k0) {  // A tile 128x32: 2 loads
    const short* src = Ap + (size_t)(bm + sr) * kstr + k0 + csw;
    short* dst = lds + buf * 12288 + t * 8;
    gll16(src, dst);
    gll16(src + (size_t)64 * kstr, dst + 2048);
  };
  auto stageB = [&](int buf, int k0) {  // B tile 256x32: 4 loads
    const short* src = Bp + (size_t)(bn + sr) * kstr + k0 + csw;
    short* dst = lds + buf * 12288 + 4096 + t * 8;
    gll16(src, dst);
    gll16(src + (size_t)64 * kstr,  dst + 2048);
    gll16(src + (size_t)128 * kstr, dst + 4096);
    gll16(src + (size_t)192 * kstr, dst + 6144);
  };
  const int swu = (g ^ ((lq >> 1) & 3)) * 8;   // read swizzle (shorts)
  auto rdA = [&](int buf, int mi) {
    const int ra = mi * 16 + lq;
    return *(const short8*)(lds + buf * 12288 + ra * 32 + swu);
  };
  auto rdB = [&](int buf, int ni) {
    const int rb = wc * 64 + ni * 16 + lq;
    return *(const short8*)(lds + buf * 12288 + 4096 + rb * 32 + swu);
  };

  stageA(0, 0);  stageB(0, 0);
  stageA(1, 32); stageB(1, 32);
  VMCNT(6);
  __builtin_amdgcn_s_barrier();

  int cur = 0;
  for (int v = 0; v < NT; ++v) {
    const int nx1 = (cur == 2) ? 0 : cur + 1;
    const int nx2 = (nx1 == 2) ? 0 : nx1 + 1;
    short8 a[8], b[4];
    #pragma unroll
    for (int mi = 0; mi < 8; ++mi) a[mi] = rdA(cur, mi);
    #pragma unroll
    for (int ni = 0; ni < 4; ++ni) b[ni] = rdB(cur, ni);
    if (v + 2 < NT) {
      stageA(nx2, (v + 2) * 32); stageB(nx2, (v + 2) * 32);
      VMCNT(6);
    } else {
      VMCNT(0);
    }
    __builtin_amdgcn_s_barrier();
    __builtin_amdgcn_s_setprio(1);
    #pragma unroll
    for (int mi = 0; mi < 8; ++mi)
      #pragma unroll
      for (int ni = 0; ni < 4; ++ni)
        acc[mi][ni] = MFMA_BF16(a[mi], b[ni], acc[mi][ni]);
    __builtin_amdgcn_s_setprio(0);
    cur = nx1;
  }

  if (EPI == 2) {
    // bias + fp32 residual direct stores
    #pragma unroll
    for (int mi = 0; mi < 8; ++mi) {
      #pragma unroll
      for (int ni = 0; ni < 4; ++ni) {
        const int col = bn + wc * 64 + ni * 16 + lq;
        const float bv = bias[col];
        #pragma unroll
        for (int r = 0; r < 4; ++r) {
          const int row = bm + mi * 16 + 4 * g + r;
          const size_t idx = (size_t)row * N + col;
          outf[idx] = acc[mi][ni][r] + bv + res[idx];
        }
      }
    }
    return;
  }

  // bf16 epilogue: (bias/gelu/qscale/none) -> LDS [128][256] bf16 -> coalesced stores
  __syncthreads();
  const float qscale = (EPI == 3 && bn < 1024) ? 0.125f * 1.44269504088896f : 1.0f;
  unsigned short* eb = (unsigned short*)lds;
  #pragma unroll
  for (int mi = 0; mi < 8; ++mi) {
    #pragma unroll
    for (int ni = 0; ni < 4; ++ni) {
      const int col = wc * 64 + ni * 16 + lq;
      const float bv = (EPI == 4) ? 0.f : bias[bn + col];
      #pragma unroll
      for (int r = 0; r < 4; ++r) {
        const int row = mi * 16 + 4 * g + r;
        float vv = acc[mi][ni][r] + bv;
        if (EPI == 1) vv = gelu_fast(vv);
        if (EPI == 3) vv *= qscale;
        eb[row * 256 + col] = f2bf(vv);
      }
    }
  }
  __syncthreads();
  #pragma unroll
  for (int it = 0; it < 16; ++it) {
    const int unit = it * 256 + t;          // 16B units over 64KB
    const int row = unit >> 5, c8 = unit & 31;
    const short8 vv = *(const short8*)(lds + unit * 8);
    *(short8*)((short*)outp + (size_t)(bm + row) * N + bn + c8 * 8) = vv;
  }
}

// ---------------- flash attention: 4-wave blocks, packed K/V fragments ----------------
__global__ __launch_bounds__(256) void attn_kernel(
    const short* __restrict__ qkv, const short* __restrict__ kp,
    const short* __restrict__ vp, unsigned short* __restrict__ y,
    const int* __restrict__ counts) {
  const int blk = blockIdx.x;
  const int slot = blk >> 3;
  const int pb = slot & 7;
  const int bh = ((slot >> 3) << 3) | (blk & 7);
  const int b = bh >> 4, h = bh & 15;
  const int w = threadIdx.x >> 6, l = threadIdx.x & 63;
  const int p = pb + 8 * w;                    // pair index 0..31
  const int lq = l & 15, g = l >> 4;
  const int qb0 = p * 16, qb1 = (63 - p) * 16;
  const int count = counts[b];

  const short* base  = qkv + (size_t)b * 1024 * 3072 + h * 64;
  const short* kbase = kp + (size_t)bh * 65536 + l * 8;   // 32 tiles x 2048 shorts
  const short* vbase = vp + (size_t)bh * 65536 + l * 8;

  short8 qf[2][2];  // [group][k-half]; B-operand col q = qb[grp]+lq (pre-scaled)
  {
    const short* qr0 = base + (size_t)(qb0 + lq) * 3072 + 8 * g;
    const short* qr1 = base + (size_t)(qb1 + lq) * 3072 + 8 * g;
    qf[0][0] = *(const short8*)qr0; qf[0][1] = *(const short8*)(qr0 + 32);
    qf[1][0] = *(const short8*)qr1; qf[1][1] = *(const short8*)(qr1 + 32);
  }

  const f32x4 z4 = {0.f, 0.f, 0.f, 0.f};
  f32x4 oacc[2][4];  // [group][dc]: O^T[d=16dc+4g+r][q]
  #pragma unroll
  for (int grp = 0; grp < 2; ++grp)
    #pragma unroll
    for (int dc = 0; dc < 4; ++dc) oacc[grp][dc] = z4;
  float mrun[2] = {-1e30f, -1e30f};
  float lrun[2] = {0.f, 0.f};                  // per-lane partial sums
  const int ncond = min((count + 31) >> 5, 8);
  const int ncausal = (qb1 + 16 - 256 + 31) >> 5;
  const int nt = ncond + ncausal;
  auto kv_of = [&](int i) { return i < ncond ? i * 32 : 256 + (i - ncond) * 32; };

  auto loadt = [&](int kv0, short8 (&kr)[4], short8 (&vr)[4]) {
    const short* kpp = kbase + (size_t)(kv0 >> 5) * 2048;
    kr[0] = *(const short8*)kpp;
    kr[1] = *(const short8*)(kpp + 512);
    kr[2] = *(const short8*)(kpp + 1024);
    kr[3] = *(const short8*)(kpp + 1536);
    const short* vpp = vbase + (size_t)(kv0 >> 5) * 2048;
    #pragma unroll
    for (int dc = 0; dc < 4; ++dc)
      vr[dc] = *(const short8*)(vpp + dc * 512);
  };

  auto compute = [&](int i, const short8 (&kr)[4], const short8 (&vr)[4]) {
    const int kv0 = kv_of(i);
    const bool isCond = (i < ncond);
    #pragma unroll
    for (int grp = 0; grp < 2; ++grp) {
      const int qb = grp ? qb1 : qb0;
      if (!isCond && kv0 >= qb + 16) continue;  // group inactive (wave-uniform)
      const bool needMask = isCond ? (kv0 + 32 > count) : (kv0 + 31 > qb);
      f32x4 sA = z4, sB = z4;  // S^T in log2 units: reg r = kv0+8g+r (A) / +4 (B)
      __builtin_amdgcn_s_setprio(1);
      sA = MFMA_BF16(kr[0], qf[grp][0], sA);
      sA = MFMA_BF16(kr[1], qf[grp][1], sA);
      sB = MFMA_BF16(kr[2], qf[grp][0], sB);
      sB = MFMA_BF16(kr[3], qf[grp][1], sB);
      __builtin_amdgcn_s_setprio(0);
      const int q = qb + lq;
      float mx = -1e30f;
      if (needMask) {
        #pragma unroll
        for (int r = 0; r < 4; ++r) {
          const int colA = kv0 + 8 * g + r, colB = colA + 4;
          const bool okA = isCond ? (colA < count) : (colA <= q);
          const bool okB = isCond ? (colB < count) : (colB <= q);
          const float vA = okA ? sA[r] : -1e30f;
          const float vB = okB ? sB[r] : -1e30f;
          sA[r] = vA; sB[r] = vB;
          mx = fmaxf(fmaxf(vA, vB), mx);
        }
      } else {
        #pragma unroll
        for (int r = 0; r < 4; ++r)
          mx = fmaxf(fmaxf(sA[r], sB[r]), mx);
      }
      mx = fmaxf(mx, __shfl_xor(mx, 16, 64));
      mx = fmaxf(mx, __shfl_xor(mx, 32, 64));
      float m = mrun[grp];
      if (!__all(mx <= m + 8.0f)) {   // defer-max: rescale only on real growth
        const float mn = fmaxf(m, mx);
        const float sf = exp2f(m - mn);   // lane-uniform
        lrun[grp] *= sf;
        #pragma unroll
        for (int dc = 0; dc < 4; ++dc)
          #pragma unroll
          for (int r = 0; r < 4; ++r) oacc[grp][dc][r] *= sf;
        mrun[grp] = mn; m = mn;
      }
      float ps = 0.f;
      #pragma unroll
      for (int r = 0; r < 4; ++r) {
        const float aa = exp2f(sA[r] - m);
        const float c2 = exp2f(sB[r] - m);
        sA[r] = aa; sB[r] = c2; ps += aa + c2;
      }
      lrun[grp] += ps;                 // per-lane partial; reduced once at the end
      union { short8 s8; __hip_bfloat162 h2[4]; } pu;  // P^T: elem j -> kv0+8g+j
      pu.h2[0] = __float22bfloat162_rn(float2{sA[0], sA[1]});
      pu.h2[1] = __float22bfloat162_rn(float2{sA[2], sA[3]});
      pu.h2[2] = __float22bfloat162_rn(float2{sB[0], sB[1]});
      pu.h2[3] = __float22bfloat162_rn(float2{sB[2], sB[3]});
      __builtin_amdgcn_s_setprio(1);
      #pragma unroll
      for (int dc = 0; dc < 4; ++dc)
        oacc[grp][dc] = MFMA_BF16(vr[dc], pu.s8, oacc[grp][dc]);
      __builtin_amdgcn_s_setprio(0);
    }
  };

  short8 kb0[4], vb0[4], kb1[4], vb1[4];
  loadt(kv_of(0), kb0, vb0);
  for (int i = 0; i < nt; i += 2) {
    if (i + 1 < nt) loadt(kv_of(i + 1), kb1, vb1);
    compute(i, kb0, vb0);
    if (i + 1 >= nt) break;
    if (i + 2 < nt) loadt(kv_of(i + 2), kb0, vb0);
    compute(i + 1, kb1, vb1);
  }

  #pragma unroll
  for (int grp = 0; grp < 2; ++grp) {
    float ls = lrun[grp];
    ls += __shfl_xor(ls, 16, 64);
    ls += __shfl_xor(ls, 32, 64);
    const float inv = 1.0f / ls;
    const int qb = grp ? qb1 : qb0;
    unsigned short* yr = y + (size_t)(b * 1024 + qb + lq) * 1024 + h * 64;
    #pragma unroll
    for (int dc = 0; dc < 4; ++dc)
      #pragma unroll
      for (int r = 0; r < 4; ++r)
        yr[16 * dc + 4 * g + r] = f2bf(oacc[grp][dc][r] * inv);
  }
}

// ---------------- launch ----------------
// Workspace (~152.1 MB):
//  [0,16M)    xn (LN1) -> kpack  | act [0,64M) after attn
//  [16M,64M)  qkv
//  [64M,80M)  yb (attn out; dead after proj) -> MLP2 partial p0
//  [80M,112M) x1 fp32 (proj output, residual for MLP2)
//  [112M,128M) vpack (pre-attn) -> hb (LN2 out; dead after MLP1) -> MLP2 partial p1
//  [128M,152M) weights | [152M,+12KB) bqkv | +16KB counts
extern "C" void kernel_launch(void* const* d_in, const int* in_sizes, int n_in,
                              void* d_out, int out_size, void* d_ws, size_t ws_size,
                              hipStream_t stream) {
  (void)in_sizes; (void)n_in; (void)out_size; (void)ws_size;
  const float* x     = (const float*)d_in[0];
  const float* ln1_g = (const float*)d_in[1];
  const float* ln1_b = (const float*)d_in[2];
  const float* Wq    = (const float*)d_in[3];
  const float* bq    = (const float*)d_in[4];
  const float* Wk    = (const float*)d_in[5];
  const float* bk    = (const float*)d_in[6];
  const float* Wv    = (const float*)d_in[7];
  const float* bv    = (const float*)d_in[8];
  const float* Wp    = (const float*)d_in[9];
  const float* bp    = (const float*)d_in[10];
  const float* ln2_g = (const float*)d_in[11];
  const float* ln2_b = (const float*)d_in[12];
  const float* W1    = (const float*)d_in[13];
  const float* b1    = (const float*)d_in[14];
  const float* W2    = (const float*)d_in[15];
  const float* b2    = (const float*)d_in[16];
  const int* cond_mask = (const int*)d_in[17];

  char* ws = (char*)d_ws;
  const size_t MB = 1u << 20;
  short* xn    = (short*)(ws + 0);
  short* kpack = (short*)(ws + 0);          // after xn dead
  short* qkv   = (short*)(ws + 16 * MB);
  short* act   = (short*)(ws + 0);          // after attn
  unsigned short* yb = (unsigned short*)(ws + 64 * MB);
  unsigned short* part0 = (unsigned short*)(ws + 64 * MB);   // after proj (yb dead)
  float* x1    = (float*)(ws + 80 * MB);
  short* vpack = (short*)(ws + 112 * MB);   // pre-attn (hb region)
  short* hb    = (short*)(ws + 112 * MB);
  unsigned short* part1 = (unsigned short*)(ws + 112 * MB);  // after MLP1 (hb dead)
  short* wqkvT = (short*)(ws + 128 * MB);
  short* wpT   = (short*)(ws + 134 * MB);
  short* w1T   = (short*)(ws + 136 * MB);
  short* w2T   = (short*)(ws + 144 * MB);
  float* bqkv  = (float*)(ws + 152 * MB);
  int* counts  = (int*)(ws + 152 * MB + 16384);

  const dim3 tb(32, 8);
  prep_kernel<<<20, 256, 0, stream>>>(cond_mask, counts, bq, bk, bv, bqkv);
  transpose4_kernel<<<dim3(32, 32, 4), tb, 0, stream>>>(Wq, Wk, Wv, Wp,
                                                        (unsigned short*)wqkvT,
                                                        (unsigned short*)wpT);
  transpose_kernel<<<dim3(128, 32), tb, 0, stream>>>(W1, (unsigned short*)w1T, 1024, 4096);
  transpose_kernel<<<dim3(32, 128), tb, 0, stream>>>(W2, (unsigned short*)w2T, 4096, 1024);
  ln_kernel<<<8192, 256, 0, stream>>>(x, ln1_g, ln1_b, (unsigned short*)xn);

  // QKV: M=8192 N=3072 K=1024, 768 blocks; Q columns pre-scaled (EPI 3)
  gemm128_kernel<3><<<768, 256, 0, stream>>>(xn, wqkvT, bqkv, 3072, 1024, 1024, 64, 0,
                                             (unsigned short*)qkv, nullptr, nullptr, nullptr);
  kvpack_kernel<<<4096, 64, 0, stream>>>(qkv, kpack, vpack);
  attn_kernel<<<1024, 256, 0, stream>>>(qkv, kpack, vpack, yb, counts);
  // proj: M=8192 N=1024 K=1024, 256 blocks, fp32 + residual (EPI 2)
  gemm128_kernel<2><<<256, 256, 0, stream>>>((const short*)yb, wpT, bp, 1024, 1024, 1024, 64, 0,
                                             nullptr, nullptr, x1, x);
  ln_kernel<<<8192, 256, 0, stream>>>(x1, ln2_g, ln2_b, (unsigned short*)hb);
  // MLP1: M=8192 N=4096 K=1024, 1024 blocks, gelu_fast (EPI 1)
  gemm128_kernel<1><<<1024, 256, 0, stream>>>(hb, w1T, b1, 4096, 1024, 1024, 64, 0,
                                              (unsigned short*)act, nullptr, nullptr, nullptr);
  // MLP2 split-K: M=8192 N=1024, K=4096 -> 2 slices of 2048; 512 blocks (EPI 4)
  gemm128_kernel<4><<<512, 256, 0, stream>>>(act, w2T, nullptr, 1024, 2048, 4096, 64, 2048,
                                             part0, part1, nullptr, nullptr);
  // reduce: out = p0 + p1 + b2 + x1
  red_kernel<<<8192, 256, 0, stream>>>(part0, part1, b2, x1, (float*)d_out);
}

// Round 22
// 377.965 us; speedup vs baseline: 1.0953x; 1.0298x over previous
//
#include <hip/hip_runtime.h>
#include <hip/hip_bf16.h>
#include <cstdint>
#include <cstddef>

// ---------------- types / helpers ----------------
typedef __attribute__((ext_vector_type(8))) short short8;   // 8 x bf16 (4 VGPRs)
typedef __attribute__((ext_vector_type(4))) float f32x4;    // MFMA accumulator
typedef __attribute__((ext_vector_type(4))) unsigned short us4;

#define MFMA_BF16(a, b, c) __builtin_amdgcn_mfma_f32_16x16x32_bf16((a), (b), (c), 0, 0, 0)
#define VMCNT(n) asm volatile("s_waitcnt vmcnt(" #n ")" ::: "memory")

__device__ __forceinline__ unsigned short f2bf(float f) {  // fp32 -> bf16 RNE
  unsigned int u = __float_as_uint(f);
  u += 0x7FFFu + ((u >> 16) & 1u);
  return (unsigned short)(u >> 16);
}

// tanh-form gelu via HW exp2/rcp (~8 VALU vs ~40+ for erff+div).
__device__ __forceinline__ float gelu_fast(float v) {
  const float u = v * (0.79788456f + 0.03567741f * v * v);
  const float e = exp2f(u * 2.88539008f);          // exp(2u)
  return v - v * __builtin_amdgcn_rcpf(e + 1.0f);
}

typedef const void __attribute__((address_space(1)))* as1_cvp;
typedef void __attribute__((address_space(3)))* as3_vp;
// Always declared (host pass parses device fns); body device-only.
__device__ __forceinline__ void gll16(const short* g, short* l) {
#if defined(__HIP_DEVICE_COMPILE__)
  __builtin_amdgcn_global_load_lds((as1_cvp)g, (as3_vp)l, 16, 0, 0);
#else
  (void)g; (void)l;
#endif
}

// ---------------- merged prep: blocks 0..11 pack bias, 12..19 count ----------------
__global__ void prep_kernel(const int* __restrict__ cm, int* __restrict__ counts,
                            const float* __restrict__ bq, const float* __restrict__ bk,
                            const float* __restrict__ bv, float* __restrict__ dst) {
  const int t = threadIdx.x;
  if (blockIdx.x < 12) {
    const int i = blockIdx.x * 256 + t;
    dst[i] = (i < 1024) ? bq[i] : (i < 2048 ? bk[i - 1024] : bv[i - 2048]);
    return;
  }
  __shared__ int sd[256];
  const int b = blockIdx.x - 12;
  int s = 0;
  for (int i = t; i < 1024; i += 256) s += cm[b * 1024 + i];
  sd[t] = s; __syncthreads();
  for (int k = 128; k > 0; k >>= 1) { if (t < k) sd[t] += sd[t + k]; __syncthreads(); }
  if (t == 0) counts[b] = sd[0];
}

// merged 4x 1024x1024 transpose: z = {Wq, Wk, Wv, Wp}
__global__ void transpose4_kernel(const float* __restrict__ Wq, const float* __restrict__ Wk,
                                  const float* __restrict__ Wv, const float* __restrict__ Wp,
                                  unsigned short* __restrict__ wqkvT,
                                  unsigned short* __restrict__ wpT) {
  __shared__ float tile[32][33];
  const int z = blockIdx.z;
  const float* src = (z == 0) ? Wq : (z == 1) ? Wk : (z == 2) ? Wv : Wp;
  unsigned short* dst = (z < 3) ? wqkvT + (size_t)z * 1024 * 1024 : wpT;
  const int c0 = blockIdx.x * 32, r0 = blockIdx.y * 32;
  const int tx = threadIdx.x, ty = threadIdx.y;
  #pragma unroll
  for (int i = ty; i < 32; i += 8)
    tile[i][tx] = src[(size_t)(r0 + i) * 1024 + (c0 + tx)];
  __syncthreads();
  #pragma unroll
  for (int i = ty; i < 32; i += 8)
    dst[(size_t)(c0 + i) * 1024 + (r0 + tx)] = f2bf(tile[tx][i]);
}

// src fp32 [R][C] -> dst bf16 [C][R]  (W1, W2)
__global__ void transpose_kernel(const float* __restrict__ src, unsigned short* __restrict__ dst,
                                 int R, int C) {
  __shared__ float tile[32][33];
  const int c0 = blockIdx.x * 32, r0 = blockIdx.y * 32;
  const int tx = threadIdx.x, ty = threadIdx.y;
  #pragma unroll
  for (int i = ty; i < 32; i += 8)
    tile[i][tx] = src[(size_t)(r0 + i) * C + (c0 + tx)];
  __syncthreads();
  #pragma unroll
  for (int i = ty; i < 32; i += 8)
    dst[(size_t)(c0 + i) * R + (r0 + tx)] = f2bf(tile[tx][i]);
}

// LayerNorm over rows of 1024 fp32 -> bf16
__global__ __launch_bounds__(256) void ln_kernel(const float* __restrict__ in,
                                                 const float* __restrict__ gw,
                                                 const float* __restrict__ bw,
                                                 unsigned short* __restrict__ out) {
  const int row = blockIdx.x, t = threadIdx.x;
  const float4 v = ((const float4*)(in + (size_t)row * 1024))[t];
  float s = v.x + v.y + v.z + v.w;
  float ss = v.x * v.x + v.y * v.y + v.z * v.z + v.w * v.w;
  #pragma unroll
  for (int o = 32; o >= 1; o >>= 1) { s += __shfl_down(s, o, 64); ss += __shfl_down(ss, o, 64); }
  __shared__ float red[8];
  if ((t & 63) == 0) { red[t >> 6] = s; red[4 + (t >> 6)] = ss; }
  __syncthreads();
  const float S  = red[0] + red[1] + red[2] + red[3];
  const float SS = red[4] + red[5] + red[6] + red[7];
  const float mu = S * (1.0f / 1024.0f);
  const float var = SS * (1.0f / 1024.0f) - mu * mu;
  const float rs = rsqrtf(var + 1e-5f);
  const int c = t * 4;
  const float4 g4 = ((const float4*)gw)[t];
  const float4 b4 = ((const float4*)bw)[t];
  us4 o4;
  o4[0] = f2bf((v.x - mu) * rs * g4.x + b4.x);
  o4[1] = f2bf((v.y - mu) * rs * g4.y + b4.y);
  o4[2] = f2bf((v.z - mu) * rs * g4.z + b4.z);
  o4[3] = f2bf((v.w - mu) * rs * g4.w + b4.w);
  *(us4*)(out + (size_t)row * 1024 + c) = o4;
}

// split-K reduce: out = p0 + p1 + bias + res (fp32), N=1024 columns
__global__ __launch_bounds__(256) void red_kernel(
    const unsigned short* __restrict__ p0, const unsigned short* __restrict__ p1,
    const float* __restrict__ bias, const float* __restrict__ res,
    float* __restrict__ out) {
  const int i = (blockIdx.x * 256 + threadIdx.x) * 4;
  const us4 a = *(const us4*)(p0 + i);
  const us4 b = *(const us4*)(p1 + i);
  const float4 r = *(const float4*)(res + i);
  const float4 bv = *(const float4*)(bias + (i & 1023));
  float4 o;
  o.x = __uint_as_float((unsigned)a[0] << 16) + __uint_as_float((unsigned)b[0] << 16) + bv.x + r.x;
  o.y = __uint_as_float((unsigned)a[1] << 16) + __uint_as_float((unsigned)b[1] << 16) + bv.y + r.y;
  o.z = __uint_as_float((unsigned)a[2] << 16) + __uint_as_float((unsigned)b[2] << 16) + bv.z + r.z;
  o.w = __uint_as_float((unsigned)a[3] << 16) + __uint_as_float((unsigned)b[3] << 16) + bv.w + r.w;
  *(float4*)(out + i) = o;
}

// ---------------- unified GEMM 128x256, BK=32, 256 threads, 2 blocks/CU ----------------
// C[M,N] = A[M,K]*BT[N,K]^T (+bias). kstr = row stride (elements); K = extent.
// 4 waves, wave tile 128x64. 3-buffer LDS (3 x 24KB = 72KB). Per K-step:
// 12 ds_read_b128 -> 32 MFMAs; stage 6 gll16 into buf v+2; VMCNT(6); 1 barrier.
// EPI 0: ->bf16; 1: gelu->bf16; 2: +res(fp32)->fp32;
// 3: QKV fused epilogue — Q region (bn<1024): qscale -> outb linear;
//    K region (1024<=bn<2048): store units directly into kpack fragment slots (outb2);
//    V region (bn>=2048): gather transposed fragments from the eb LDS tile -> vpack (outb3);
// 4: split-K partial (no bias, bf16; grid 2x: slice = wid>>8, out slice? outb:outb2).
template <int EPI>
__global__ __launch_bounds__(256, 2) void gemm128_kernel(
    const short* __restrict__ A, const short* __restrict__ BT,
    const float* __restrict__ bias, int N, int K, int kstr, int gm, int skoff,
    unsigned short* __restrict__ outb, unsigned short* __restrict__ outb2,
    unsigned short* __restrict__ outb3,
    float* __restrict__ outf, const float* __restrict__ res) {
  __shared__ alignas(16) short lds[36864];  // 3 bufs x 12288 shorts (A 4096 + B 8192)
  const int t = threadIdx.x;
  const int l = t & 63, w = t >> 6;         // wave w = col slice wc
  const int lq = l & 15, g = l >> 4;
  const int wc = w;
  const int cpx = (int)gridDim.x >> 3;
  int wid = ((int)blockIdx.x & 7) * cpx + ((int)blockIdx.x >> 3);
  int slice = 0;
  if (EPI == 4) { slice = wid >> 8; wid &= 255; }
  const short* Ap = A + (size_t)slice * skoff;
  const short* Bp = BT + (size_t)slice * skoff;
  unsigned short* outp = (EPI == 4 && slice) ? outb2 : outb;
  const int bm = (wid % gm) * 128, bn = (wid / gm) * 256;
  const int NT = K >> 5;

  const int csw = ((t & 3) ^ ((t >> 3) & 3)) * 8;   // pre-swizzled global k-offset (shorts)
  const int sr = t >> 2;                             // 0..63 staging row base

  const f32x4 z4 = {0.f, 0.f, 0.f, 0.f};
  f32x4 acc[8][4];
  #pragma unroll
  for (int i = 0; i < 8; i++)
    #pragma unroll
    for (int j = 0; j < 4; j++) acc[i][j] = z4;

  auto stageA = [&](int buf, int k0) {  // A tile 128x32: 2 loads
    const short* src = Ap + (size_t)(bm + sr) * kstr + k0 + csw;
    short* dst = lds + buf * 12288 + t * 8;
    gll16(src, dst);
    gll16(src + (size_t)64 * kstr, dst + 2048);
  };
  auto stageB = [&](int buf, int k0) {  // B tile 256x32: 4 loads
    const short* src = Bp + (size_t)(bn + sr) * kstr + k0 + csw;
    short* dst = lds + buf * 12288 + 4096 + t * 8;
    gll16(src, dst);
    gll16(src + (size_t)64 * kstr,  dst + 2048);
    gll16(src + (size_t)128 * kstr, dst + 4096);
    gll16(src + (size_t)192 * kstr, dst + 6144);
  };
  const int swu = (g ^ ((lq >> 1) & 3)) * 8;   // read swizzle (shorts)
  auto rdA = [&](int buf, int mi) {
    const int ra = mi * 16 + lq;
    return *(const short8*)(lds + buf * 12288 + ra * 32 + swu);
  };
  auto rdB = [&](int buf, int ni) {
    const int rb = wc * 64 + ni * 16 + lq;
    return *(const short8*)(lds + buf * 12288 + 4096 + rb * 32 + swu);
  };

  stageA(0, 0);  stageB(0, 0);
  stageA(1, 32); stageB(1, 32);
  VMCNT(6);
  __builtin_amdgcn_s_barrier();

  int cur = 0;
  for (int v = 0; v < NT; ++v) {
    const int nx1 = (cur == 2) ? 0 : cur + 1;
    const int nx2 = (nx1 == 2) ? 0 : nx1 + 1;
    short8 a[8], b[4];
    #pragma unroll
    for (int mi = 0; mi < 8; ++mi) a[mi] = rdA(cur, mi);
    #pragma unroll
    for (int ni = 0; ni < 4; ++ni) b[ni] = rdB(cur, ni);
    if (v + 2 < NT) {
      stageA(nx2, (v + 2) * 32); stageB(nx2, (v + 2) * 32);
      VMCNT(6);
    } else {
      VMCNT(0);
    }
    __builtin_amdgcn_s_barrier();
    __builtin_amdgcn_s_setprio(1);
    #pragma unroll
    for (int mi = 0; mi < 8; ++mi)
      #pragma unroll
      for (int ni = 0; ni < 4; ++ni)
        acc[mi][ni] = MFMA_BF16(a[mi], b[ni], acc[mi][ni]);
    __builtin_amdgcn_s_setprio(0);
    cur = nx1;
  }

  if (EPI == 2) {
    // bias + fp32 residual direct stores
    #pragma unroll
    for (int mi = 0; mi < 8; ++mi) {
      #pragma unroll
      for (int ni = 0; ni < 4; ++ni) {
        const int col = bn + wc * 64 + ni * 16 + lq;
        const float bv = bias[col];
        #pragma unroll
        for (int r = 0; r < 4; ++r) {
          const int row = bm + mi * 16 + 4 * g + r;
          const size_t idx = (size_t)row * N + col;
          outf[idx] = acc[mi][ni][r] + bv + res[idx];
        }
      }
    }
    return;
  }

  // bf16 epilogue: (bias/gelu/qscale/none) -> LDS [128][256] bf16 -> stores
  __syncthreads();
  const float qscale = (EPI == 3 && bn < 1024) ? 0.125f * 1.44269504088896f : 1.0f;
  unsigned short* eb = (unsigned short*)lds;
  #pragma unroll
  for (int mi = 0; mi < 8; ++mi) {
    #pragma unroll
    for (int ni = 0; ni < 4; ++ni) {
      const int col = wc * 64 + ni * 16 + lq;
      const float bv = (EPI == 4) ? 0.f : bias[bn + col];
      #pragma unroll
      for (int r = 0; r < 4; ++r) {
        const int row = mi * 16 + 4 * g + r;
        float vv = acc[mi][ni][r] + bv;
        if (EPI == 1) vv = gelu_fast(vv);
        if (EPI == 3) vv *= qscale;
        eb[row * 256 + col] = f2bf(vv);
      }
    }
  }
  __syncthreads();

  if (EPI == 3 && bn >= 1024 && bn < 2048) {
    // K region -> kpack fragments (outb2). kp[bh][ti][frag][lane][8].
    // kvr -> lq=(kvr>>3)*4+(kvr&3), hi=(kvr>>2)&1; d-chunk c: g=c&3, fsel=c>>2;
    // frag = 2*hi + fsel; lane = 16*g + lq.  (verified vs kvpack mapping)
    const int bb = bm >> 10;
    #pragma unroll
    for (int it = 0; it < 16; ++it) {
      const int unit = it * 256 + t;
      const int row = unit >> 5, c8 = unit & 31;
      const int col = c8 * 8;
      const int hh = (bn - 1024 + col) >> 6;
      const int c = (col & 63) >> 3;
      const int tt = (bm + row) & 1023;
      const int ti = tt >> 5, kvr = tt & 31;
      const int lqk = ((kvr >> 3) << 2) | (kvr & 3);
      const int frag = (((kvr >> 2) & 1) << 1) | (c >> 2);
      const int lane = ((c & 3) << 4) | lqk;
      const short8 vv = *(const short8*)(lds + unit * 8);
      *(short8*)((short*)outb2 + ((size_t)(bb * 16 + hh) * 32 + ti) * 2048
                 + frag * 512 + lane * 8) = vv;
    }
    return;
  }
  if (EPI == 3 && bn >= 2048) {
    // V region -> vpack fragments (outb3), transposed gather from eb tile.
    // vp[bh][gt][dc][lane][8]: elem j = V[kv0+8g+j][16dc+lq].
    const int bb = bm >> 10;
    const int bt = (bm & 1023) >> 5;   // base kv tile of this 128-row block
    #pragma unroll
    for (int it = 0; it < 16; ++it) {
      const int u = it * 256 + t;
      const int s = u >> 8;            // subtile 0..15
      const int til = s & 3, hl = s >> 2;
      const int fl = u & 255;
      const int dc = fl >> 6, lane = fl & 63;
      const int lqv = lane & 15, gv = lane >> 4;
      short8 vv;
      #pragma unroll
      for (int j = 0; j < 8; ++j)
        vv[j] = (short)eb[(til * 32 + 8 * gv + j) * 256 + hl * 64 + 16 * dc + lqv];
      const int hh = ((bn - 2048) >> 6) + hl;
      *(short8*)((short*)outb3 + ((size_t)(bb * 16 + hh) * 32 + (bt + til)) * 2048
                 + dc * 512 + lane * 8) = vv;
    }
    return;
  }

  #pragma unroll
  for (int it = 0; it < 16; ++it) {
    const int unit = it * 256 + t;          // 16B units over 64KB
    const int row = unit >> 5, c8 = unit & 31;
    const short8 vv = *(const short8*)(lds + unit * 8);
    *(short8*)((short*)outp + (size_t)(bm + row) * N + bn + c8 * 8) = vv;
  }
}

// ---------------- flash attention: 4-wave blocks, packed K/V fragments ----------------
__global__ __launch_bounds__(256) void attn_kernel(
    const short* __restrict__ qkv, const short* __restrict__ kp,
    const short* __restrict__ vp, unsigned short* __restrict__ y,
    const int* __restrict__ counts) {
  const int blk = blockIdx.x;
  const int slot = blk >> 3;
  const int pb = slot & 7;
  const int bh = ((slot >> 3) << 3) | (blk & 7);
  const int b = bh >> 4, h = bh & 15;
  const int w = threadIdx.x >> 6, l = threadIdx.x & 63;
  const int p = pb + 8 * w;                    // pair index 0..31
  const int lq = l & 15, g = l >> 4;
  const int qb0 = p * 16, qb1 = (63 - p) * 16;
  const int count = counts[b];

  const short* base  = qkv + (size_t)b * 1024 * 3072 + h * 64;
  const short* kbase = kp + (size_t)bh * 65536 + l * 8;   // 32 tiles x 2048 shorts
  const short* vbase = vp + (size_t)bh * 65536 + l * 8;

  short8 qf[2][2];  // [group][k-half]; B-operand col q = qb[grp]+lq (pre-scaled)
  {
    const short* qr0 = base + (size_t)(qb0 + lq) * 3072 + 8 * g;
    const short* qr1 = base + (size_t)(qb1 + lq) * 3072 + 8 * g;
    qf[0][0] = *(const short8*)qr0; qf[0][1] = *(const short8*)(qr0 + 32);
    qf[1][0] = *(const short8*)qr1; qf[1][1] = *(const short8*)(qr1 + 32);
  }

  const f32x4 z4 = {0.f, 0.f, 0.f, 0.f};
  f32x4 oacc[2][4];  // [group][dc]: O^T[d=16dc+4g+r][q]
  #pragma unroll
  for (int grp = 0; grp < 2; ++grp)
    #pragma unroll
    for (int dc = 0; dc < 4; ++dc) oacc[grp][dc] = z4;
  float mrun[2] = {-1e30f, -1e30f};
  float lrun[2] = {0.f, 0.f};                  // per-lane partial sums
  const int ncond = min((count + 31) >> 5, 8);
  const int ncausal = (qb1 + 16 - 256 + 31) >> 5;
  const int nt = ncond + ncausal;
  auto kv_of = [&](int i) { return i < ncond ? i * 32 : 256 + (i - ncond) * 32; };

  auto loadt = [&](int kv0, short8 (&kr)[4], short8 (&vr)[4]) {
    const short* kpp = kbase + (size_t)(kv0 >> 5) * 2048;
    kr[0] = *(const short8*)kpp;
    kr[1] = *(const short8*)(kpp + 512);
    kr[2] = *(const short8*)(kpp + 1024);
    kr[3] = *(const short8*)(kpp + 1536);
    const short* vpp = vbase + (size_t)(kv0 >> 5) * 2048;
    #pragma unroll
    for (int dc = 0; dc < 4; ++dc)
      vr[dc] = *(const short8*)(vpp + dc * 512);
  };

  auto compute = [&](int i, const short8 (&kr)[4], const short8 (&vr)[4]) {
    const int kv0 = kv_of(i);
    const bool isCond = (i < ncond);
    #pragma unroll
    for (int grp = 0; grp < 2; ++grp) {
      const int qb = grp ? qb1 : qb0;
      if (!isCond && kv0 >= qb + 16) continue;  // group inactive (wave-uniform)
      const bool needMask = isCond ? (kv0 + 32 > count) : (kv0 + 31 > qb);
      f32x4 sA = z4, sB = z4;  // S^T in log2 units: reg r = kv0+8g+r (A) / +4 (B)
      __builtin_amdgcn_s_setprio(1);
      sA = MFMA_BF16(kr[0], qf[grp][0], sA);
      sA = MFMA_BF16(kr[1], qf[grp][1], sA);
      sB = MFMA_BF16(kr[2], qf[grp][0], sB);
      sB = MFMA_BF16(kr[3], qf[grp][1], sB);
      __builtin_amdgcn_s_setprio(0);
      const int q = qb + lq;
      float mx = -1e30f;
      if (needMask) {
        #pragma unroll
        for (int r = 0; r < 4; ++r) {
          const int colA = kv0 + 8 * g + r, colB = colA + 4;
          const bool okA = isCond ? (colA < count) : (colA <= q);
          const bool okB = isCond ? (colB < count) : (colB <= q);
          const float vA = okA ? sA[r] : -1e30f;
          const float vB = okB ? sB[r] : -1e30f;
          sA[r] = vA; sB[r] = vB;
          mx = fmaxf(fmaxf(vA, vB), mx);
        }
      } else {
        #pragma unroll
        for (int r = 0; r < 4; ++r)
          mx = fmaxf(fmaxf(sA[r], sB[r]), mx);
      }
      mx = fmaxf(mx, __shfl_xor(mx, 16, 64));
      mx = fmaxf(mx, __shfl_xor(mx, 32, 64));
      float m = mrun[grp];
      if (!__all(mx <= m + 8.0f)) {   // defer-max: rescale only on real growth
        const float mn = fmaxf(m, mx);
        const float sf = exp2f(m - mn);   // lane-uniform
        lrun[grp] *= sf;
        #pragma unroll
        for (int dc = 0; dc < 4; ++dc)
          #pragma unroll
          for (int r = 0; r < 4; ++r) oacc[grp][dc][r] *= sf;
        mrun[grp] = mn; m = mn;
      }
      float ps = 0.f;
      #pragma unroll
      for (int r = 0; r < 4; ++r) {
        const float aa = exp2f(sA[r] - m);
        const float c2 = exp2f(sB[r] - m);
        sA[r] = aa; sB[r] = c2; ps += aa + c2;
      }
      lrun[grp] += ps;                 // per-lane partial; reduced once at the end
      union { short8 s8; __hip_bfloat162 h2[4]; } pu;  // P^T: elem j -> kv0+8g+j
      pu.h2[0] = __float22bfloat162_rn(float2{sA[0], sA[1]});
      pu.h2[1] = __float22bfloat162_rn(float2{sA[2], sA[3]});
      pu.h2[2] = __float22bfloat162_rn(float2{sB[0], sB[1]});
      pu.h2[3] = __float22bfloat162_rn(float2{sB[2], sB[3]});
      __builtin_amdgcn_s_setprio(1);
      #pragma unroll
      for (int dc = 0; dc < 4; ++dc)
        oacc[grp][dc] = MFMA_BF16(vr[dc], pu.s8, oacc[grp][dc]);
      __builtin_amdgcn_s_setprio(0);
    }
  };

  short8 kb0[4], vb0[4], kb1[4], vb1[4];
  loadt(kv_of(0), kb0, vb0);
  for (int i = 0; i < nt; i += 2) {
    if (i + 1 < nt) loadt(kv_of(i + 1), kb1, vb1);
    compute(i, kb0, vb0);
    if (i + 1 >= nt) break;
    if (i + 2 < nt) loadt(kv_of(i + 2), kb0, vb0);
    compute(i + 1, kb1, vb1);
  }

  #pragma unroll
  for (int grp = 0; grp < 2; ++grp) {
    float ls = lrun[grp];
    ls += __shfl_xor(ls, 16, 64);
    ls += __shfl_xor(ls, 32, 64);
    const float inv = 1.0f / ls;
    const int qb = grp ? qb1 : qb0;
    unsigned short* yr = y + (size_t)(b * 1024 + qb + lq) * 1024 + h * 64;
    #pragma unroll
    for (int dc = 0; dc < 4; ++dc)
      #pragma unroll
      for (int r = 0; r < 4; ++r)
        yr[16 * dc + 4 * g + r] = f2bf(oacc[grp][dc][r] * inv);
  }
}

// ---------------- launch ----------------
// Workspace (~152.1 MB):
//  [0,16M)    xn (LN1 out; QKV GEMM input) | act [0,64M) after attn
//  [16M,64M)  qkv (Q region live; K/V regions unused)
//  [64M,80M)  yb (attn out; dead after proj) -> MLP2 partial p0
//  [80M,96M)  kpack (QKV epi out; dead after attn) -> x1 fp32 [80M,112M) (proj out)
//  [112M,128M) vpack (QKV epi out; dead after attn) -> hb (LN2) -> MLP2 partial p1
//  [128M,152M) weights | [152M,+12KB) bqkv | +16KB counts
extern "C" void kernel_launch(void* const* d_in, const int* in_sizes, int n_in,
                              void* d_out, int out_size, void* d_ws, size_t ws_size,
                              hipStream_t stream) {
  (void)in_sizes; (void)n_in; (void)out_size; (void)ws_size;
  const float* x     = (const float*)d_in[0];
  const float* ln1_g = (const float*)d_in[1];
  const float* ln1_b = (const float*)d_in[2];
  const float* Wq    = (const float*)d_in[3];
  const float* bq    = (const float*)d_in[4];
  const float* Wk    = (const float*)d_in[5];
  const float* bk    = (const float*)d_in[6];
  const float* Wv    = (const float*)d_in[7];
  const float* bv    = (const float*)d_in[8];
  const float* Wp    = (const float*)d_in[9];
  const float* bp    = (const float*)d_in[10];
  const float* ln2_g = (const float*)d_in[11];
  const float* ln2_b = (const float*)d_in[12];
  const float* W1    = (const float*)d_in[13];
  const float* b1    = (const float*)d_in[14];
  const float* W2    = (const float*)d_in[15];
  const float* b2    = (const float*)d_in[16];
  const int* cond_mask = (const int*)d_in[17];

  char* ws = (char*)d_ws;
  const size_t MB = 1u << 20;
  short* xn    = (short*)(ws + 0);
  short* qkv   = (short*)(ws + 16 * MB);
  short* act   = (short*)(ws + 0);          // after attn (xn dead)
  unsigned short* yb = (unsigned short*)(ws + 64 * MB);
  unsigned short* part0 = (unsigned short*)(ws + 64 * MB);   // after proj (yb dead)
  short* kpack = (short*)(ws + 80 * MB);    // QKV epi out; dead after attn
  float* x1    = (float*)(ws + 80 * MB);    // proj out (after attn)
  short* vpack = (short*)(ws + 112 * MB);   // QKV epi out; dead after attn
  short* hb    = (short*)(ws + 112 * MB);
  unsigned short* part1 = (unsigned short*)(ws + 112 * MB);  // after MLP1 (hb dead)
  short* wqkvT = (short*)(ws + 128 * MB);
  short* wpT   = (short*)(ws + 134 * MB);
  short* w1T   = (short*)(ws + 136 * MB);
  short* w2T   = (short*)(ws + 144 * MB);
  float* bqkv  = (float*)(ws + 152 * MB);
  int* counts  = (int*)(ws + 152 * MB + 16384);

  const dim3 tb(32, 8);
  prep_kernel<<<20, 256, 0, stream>>>(cond_mask, counts, bq, bk, bv, bqkv);
  transpose4_kernel<<<dim3(32, 32, 4), tb, 0, stream>>>(Wq, Wk, Wv, Wp,
                                                        (unsigned short*)wqkvT,
                                                        (unsigned short*)wpT);
  transpose_kernel<<<dim3(128, 32), tb, 0, stream>>>(W1, (unsigned short*)w1T, 1024, 4096);
  transpose_kernel<<<dim3(32, 128), tb, 0, stream>>>(W2, (unsigned short*)w2T, 4096, 1024);
  ln_kernel<<<8192, 256, 0, stream>>>(x, ln1_g, ln1_b, (unsigned short*)xn);

  // QKV: M=8192 N=3072 K=1024, 768 blocks; fused epilogue writes Q->qkv,
  // K->kpack fragments, V->vpack fragments (EPI 3)
  gemm128_kernel<3><<<768, 256, 0, stream>>>(xn, wqkvT, bqkv, 3072, 1024, 1024, 64, 0,
                                             (unsigned short*)qkv, (unsigned short*)kpack,
                                             (unsigned short*)vpack, nullptr, nullptr);
  attn_kernel<<<1024, 256, 0, stream>>>(qkv, kpack, vpack, yb, counts);
  // proj: M=8192 N=1024 K=1024, 256 blocks, fp32 + residual (EPI 2)
  gemm128_kernel<2><<<256, 256, 0, stream>>>((const short*)yb, wpT, bp, 1024, 1024, 1024, 64, 0,
                                             nullptr, nullptr, nullptr, x1, x);
  ln_kernel<<<8192, 256, 0, stream>>>(x1, ln2_g, ln2_b, (unsigned short*)hb);
  // MLP1: M=8192 N=4096 K=1024, 1024 blocks, gelu_fast (EPI 1)
  gemm128_kernel<1><<<1024, 256, 0, stream>>>(hb, w1T, b1, 4096, 1024, 1024, 64, 0,
                                              (unsigned short*)act, nullptr, nullptr,
                                              nullptr, nullptr);
  // MLP2 split-K: M=8192 N=1024, K=4096 -> 2 slices of 2048; 512 blocks (EPI 4)
  gemm128_kernel<4><<<512, 256, 0, stream>>>(act, w2T, nullptr, 1024, 2048, 4096, 64, 2048,
                                             part0, part1, nullptr, nullptr, nullptr);
  // reduce: out = p0 + p1 + b2 + x1
  red_kernel<<<8192, 256, 0, stream>>>(part0, part1, b2, x1, (float*)d_out);
}